// Round 1
// baseline (27167.371 us; speedup 1.0000x reference)
//
#include <hip/hip_runtime.h>
#include <math.h>

// ---------------------------------------------------------------------------
// fp32 baseline implementation. Shapes: B=16, T=1024, Din=64, D=512, Dff=2048,
// L=4, H=8, dh=64, TOP_K=32. M = B*T = 16384 rows everywhere.
// ---------------------------------------------------------------------------

#define TILE 64

// EPI: 0 = none, 1 = +bias, 2 = +bias +exact GELU, 3 = +bias +pos_encoding
template<int EPI>
__global__ __launch_bounds__(256) void gemm_kernel(const float* __restrict__ A,
    const float* __restrict__ B, const float* __restrict__ bias,
    float* __restrict__ C, int M, int N, int K) {
  __shared__ float As[16][TILE + 1];   // [k][m]
  __shared__ float Bs[16][TILE + 1];   // [k][n]
  const int tid = threadIdx.x;
  const int tx = tid & 15, ty = tid >> 4;
  const int bn = blockIdx.x * TILE, bm = blockIdx.y * TILE;
  float acc[4][4] = {};
  for (int k0 = 0; k0 < K; k0 += 16) {
#pragma unroll
    for (int i = 0; i < 4; i++) {
      int idx = tid + i * 256;             // 0..1023
      int am = idx >> 4, ak = idx & 15;    // A tile 64x16
      As[ak][am] = A[(size_t)(bm + am) * K + k0 + ak];
      int bk = idx >> 6, bnn = idx & 63;   // B tile 16x64
      Bs[bk][bnn] = B[(size_t)(k0 + bk) * N + bn + bnn];
    }
    __syncthreads();
#pragma unroll
    for (int kk = 0; kk < 16; kk++) {
      float a[4], b[4];
#pragma unroll
      for (int i = 0; i < 4; i++) a[i] = As[kk][ty * 4 + i];
#pragma unroll
      for (int j = 0; j < 4; j++) b[j] = Bs[kk][tx * 4 + j];
#pragma unroll
      for (int i = 0; i < 4; i++)
#pragma unroll
        for (int j = 0; j < 4; j++) acc[i][j] = fmaf(a[i], b[j], acc[i][j]);
    }
    __syncthreads();
  }
#pragma unroll
  for (int i = 0; i < 4; i++) {
    int m = bm + ty * 4 + i;
    float4 o;
    float* op = &o.x;
#pragma unroll
    for (int j = 0; j < 4; j++) {
      int n = bn + tx * 4 + j;
      float vv = acc[i][j];
      if (EPI >= 1) vv += bias[n];
      if (EPI == 2) vv = 0.5f * vv * (1.0f + erff(vv * 0.70710678118654752f));
      if (EPI == 3) {
        int t = m & 1023;                         // row = b*T + t
        float fr = expf((float)(n & ~1) * (-9.210340371976184f / 512.0f));
        float ang = (float)t * fr;
        vv += (n & 1) ? cosf(ang) : sinf(ang);
      }
      op[j] = vv;
    }
    *(float4*)(&C[(size_t)m * N + bn + tx * 4]) = o;
  }
}

// Sparse top-32 attention. One wave per (b,h,t) row; 4 waves per block.
// q,k,v,out layout: [B,T,D] with head h occupying columns h*64..h*64+63.
__global__ __launch_bounds__(256) void attn_kernel(const float* __restrict__ q,
    const float* __restrict__ k, const float* __restrict__ v,
    float* __restrict__ out) {
  const int T = 1024, DM = 512, DH = 64;
  const int wave = threadIdx.x >> 6, lane = threadIdx.x & 63;
  const int bh = blockIdx.x >> 8, tg = blockIdx.x & 255;  // grid = 128*256
  const int b = bh >> 3, hh = bh & 7;
  const int t = tg * 4 + wave;
  const size_t rowq = ((size_t)b * T + t) * DM + hh * DH;
  const float* kb = k + (size_t)b * T * DM + hh * DH;
  const float* vb = v + (size_t)b * T * DM + hh * DH;

  __shared__ __align__(16) float qs[4][64];
  __shared__ int   sidx[4][128];
  __shared__ float sval[4][128];

  qs[wave][lane] = q[rowq + lane];
  __syncthreads();

  // scores: sc[j] corresponds to s = j*64 + lane
  float sc[16];
#pragma unroll
  for (int j = 0; j < 16; j++) {
    const float4* kr = (const float4*)(kb + (size_t)(j * 64 + lane) * DM);
    const float4* qr = (const float4*)qs[wave];
    float acc = 0.f;
#pragma unroll
    for (int d = 0; d < 16; d++) {
      float4 kv = kr[d], qv = qr[d];
      acc = fmaf(qv.x, kv.x, acc); acc = fmaf(qv.y, kv.y, acc);
      acc = fmaf(qv.z, kv.z, acc); acc = fmaf(qv.w, kv.w, acc);
    }
    sc[j] = acc * 0.125f;   // / sqrt(64)
  }

  // exact kth (32nd) largest via 32 argmax extractions (handles ties exactly)
  float wk[16];
#pragma unroll
  for (int j = 0; j < 16; j++) wk[j] = sc[j];
  float kth = 0.f, mmax = 0.f;
  for (int it = 0; it < 32; it++) {
    float best = wk[0]; int bj = 0;
#pragma unroll
    for (int j = 1; j < 16; j++) if (wk[j] > best) { best = wk[j]; bj = j; }
    float bv = best; int bl = lane;
#pragma unroll
    for (int off = 32; off; off >>= 1) {
      float ov = __shfl_xor(bv, off);
      int   ol = __shfl_xor(bl, off);
      if (ov > bv || (ov == bv && ol < bl)) { bv = ov; bl = ol; }
    }
    if (it == 0) mmax = bv;
    kth = bv;
    if (bl == lane) wk[bj] = -INFINITY;   // remove exactly one instance
  }

  // softmax over kept entries (sc >= kth)
  float p[16]; float psum = 0.f;
#pragma unroll
  for (int j = 0; j < 16; j++) {
    float e = (sc[j] >= kth) ? __expf(sc[j] - mmax) : 0.f;
    p[j] = e; psum += e;
  }
#pragma unroll
  for (int off = 32; off; off >>= 1) psum += __shfl_xor(psum, off);

  // compact kept (s, p) pairs into LDS — typically exactly 32 entries
  int base = 0;
#pragma unroll
  for (int j = 0; j < 16; j++) {
    unsigned long long mk = __ballot(p[j] > 0.f);
    if (p[j] > 0.f) {
      int pos = base + (int)__popcll(mk & ((1ull << lane) - 1ull));
      if (pos < 128) { sidx[wave][pos] = j * 64 + lane; sval[wave][pos] = p[j]; }
    }
    base += (int)__popcll(mk);
  }
  int cnt = base < 128 ? base : 128;
  __syncthreads();

  // sparse PV: out[d=lane] = sum over kept s of p_s * v[s,d] / psum
  float acc = 0.f;
  float rden = 1.f / psum;
  for (int i = 0; i < cnt; i++) {
    int s = sidx[wave][i];
    acc = fmaf(sval[wave][i], vb[(size_t)s * DM + lane], acc);
  }
  out[rowq + lane] = acc * rden;
}

// h[row] = LayerNorm(h[row] + o[row]) * g + be   (wave per row, 4 rows/block)
__global__ __launch_bounds__(256) void resid_ln_kernel(float* __restrict__ h,
    const float* __restrict__ o, const float* __restrict__ g,
    const float* __restrict__ be) {
  const int wave = threadIdx.x >> 6, lane = threadIdx.x & 63;
  const size_t row = (size_t)blockIdx.x * 4 + wave;
  float* hr = h + row * 512;
  const float* orr = o + row * 512;
  float x[8]; float s = 0.f, s2 = 0.f;
#pragma unroll
  for (int j = 0; j < 8; j++) {
    float vv = hr[j * 64 + lane] + orr[j * 64 + lane];
    x[j] = vv; s += vv; s2 += vv * vv;
  }
#pragma unroll
  for (int off = 32; off; off >>= 1) { s += __shfl_xor(s, off); s2 += __shfl_xor(s2, off); }
  float mean = s * (1.f / 512.f);
  float var  = s2 * (1.f / 512.f) - mean * mean;
  float r = rsqrtf(var + 1e-5f);
#pragma unroll
  for (int j = 0; j < 8; j++) {
    int d = j * 64 + lane;
    hr[d] = (x[j] - mean) * r * g[d] + be[d];
  }
}

// final two-head readout on h[:, -1, :]
__global__ __launch_bounds__(256) void head_kernel(const float* __restrict__ h,
    const float* __restrict__ gm, const float* __restrict__ bm,
    const float* __restrict__ Wm, const float* __restrict__ cm,
    const float* __restrict__ gs, const float* __restrict__ bs,
    const float* __restrict__ Ws, const float* __restrict__ cs,
    float* __restrict__ out) {
  const int wave = threadIdx.x >> 6, lane = threadIdx.x & 63;
  const int b = blockIdx.x * 4 + wave;
  const float* hr = h + ((size_t)b * 1024 + 1023) * 512;
  float x[8]; float s = 0.f, s2 = 0.f;
#pragma unroll
  for (int j = 0; j < 8; j++) { float vv = hr[j * 64 + lane]; x[j] = vv; s += vv; s2 += vv * vv; }
#pragma unroll
  for (int off = 32; off; off >>= 1) { s += __shfl_xor(s, off); s2 += __shfl_xor(s2, off); }
  float mean = s * (1.f / 512.f);
  float var  = s2 * (1.f / 512.f) - mean * mean;
  float r = rsqrtf(var + 1e-5f);
  float am = 0.f, as = 0.f;
#pragma unroll
  for (int j = 0; j < 8; j++) {
    int d = j * 64 + lane;
    float n = (x[j] - mean) * r;
    am = fmaf(n * gm[d] + bm[d], Wm[d], am);
    as = fmaf(n * gs[d] + bs[d], Ws[d], as);
  }
#pragma unroll
  for (int off = 32; off; off >>= 1) { am += __shfl_xor(am, off); as += __shfl_xor(as, off); }
  if (lane == 0) {
    const double Z = 2.326347874040841;
    float mu  = am + cm[0];
    float scl = 1.f / (1.f + expf(-(as + cs[0])));   // * SCALE_MAX(=1)
    float esc = (float)(exp(-0.5 * Z * Z) / sqrt(2.0 * 3.14159265358979323846) / 0.01);
    out[b]      = mu;
    out[16 + b] = scl;
    out[32 + b] = mu + scl * (float)Z;
    out[48 + b] = mu + scl * esc;
  }
}

extern "C" void kernel_launch(void* const* d_in, const int* in_sizes, int n_in,
                              void* d_out, int out_size, void* d_ws, size_t ws_size,
                              hipStream_t stream) {
  const float* x    = (const float*)d_in[0];
  const float* W_in = (const float*)d_in[1];
  const float* b_in = (const float*)d_in[2];
  const float* Wq   = (const float*)d_in[3];
  const float* Wk   = (const float*)d_in[4];
  const float* Wv   = (const float*)d_in[5];
  const float* Wo   = (const float*)d_in[6];
  const float* bo   = (const float*)d_in[7];
  const float* W1   = (const float*)d_in[8];
  const float* b1   = (const float*)d_in[9];
  const float* W2   = (const float*)d_in[10];
  const float* b2   = (const float*)d_in[11];
  const float* g1   = (const float*)d_in[12];
  const float* be1  = (const float*)d_in[13];
  const float* g2   = (const float*)d_in[14];
  const float* be2  = (const float*)d_in[15];
  const float* gm   = (const float*)d_in[16];
  const float* bm   = (const float*)d_in[17];
  const float* Wm   = (const float*)d_in[18];
  const float* cm   = (const float*)d_in[19];
  const float* gs   = (const float*)d_in[20];
  const float* bs   = (const float*)d_in[21];
  const float* Ws   = (const float*)d_in[22];
  const float* cs   = (const float*)d_in[23];

  const int M = 16384, D = 512, DFF = 2048;
  float* ws = (float*)d_ws;
  float* h  = ws;                   // 16384x512
  float* bq = ws +  8388608;        // 16384x512
  float* bk = ws + 16777216;        // 16384x512
  float* bv = ws + 25165824;        // 16384x512
  float* ba = ws + 33554432;        // 16384x512
  float* bb = ws + 41943040;        // 16384x512
  float* ff = bq;                   // 16384x2048 spans bq..ba (contiguous)

  dim3 blk(256);
  dim3 gD(D / 64, M / 64);          // (8, 256)
  dim3 gF(DFF / 64, M / 64);        // (32, 256)

  // h = x @ W_in + b_in + pos_encoding
  gemm_kernel<3><<<gD, blk, 0, stream>>>(x, W_in, b_in, h, M, D, 64);

  for (int l = 0; l < 4; l++) {
    const float* wq = Wq + (size_t)l * D * D;
    const float* wk = Wk + (size_t)l * D * D;
    const float* wv = Wv + (size_t)l * D * D;
    const float* wo = Wo + (size_t)l * D * D;

    gemm_kernel<0><<<gD, blk, 0, stream>>>(h, wq, nullptr, bq, M, D, D);
    gemm_kernel<0><<<gD, blk, 0, stream>>>(h, wk, nullptr, bk, M, D, D);
    gemm_kernel<0><<<gD, blk, 0, stream>>>(h, wv, nullptr, bv, M, D, D);

    attn_kernel<<<dim3(32768), blk, 0, stream>>>(bq, bk, bv, ba);

    gemm_kernel<1><<<gD, blk, 0, stream>>>(ba, wo, bo + (size_t)l * D, bq, M, D, D);
    resid_ln_kernel<<<dim3(4096), blk, 0, stream>>>(h, bq, g1 + (size_t)l * D, be1 + (size_t)l * D);

    gemm_kernel<2><<<gF, blk, 0, stream>>>(h, W1 + (size_t)l * D * DFF, b1 + (size_t)l * DFF, ff, M, DFF, D);
    gemm_kernel<1><<<gD, blk, 0, stream>>>(ff, W2 + (size_t)l * DFF * D, b2 + (size_t)l * D, bb, M, D, DFF);
    resid_ln_kernel<<<dim3(4096), blk, 0, stream>>>(h, bb, g2 + (size_t)l * D, be2 + (size_t)l * D);
  }

  head_kernel<<<dim3(4), blk, 0, stream>>>(h, gm, bm, Wm, cm, gs, bs, Ws, cs, (float*)d_out);
}

// Round 2
// 9740.948 us; speedup vs baseline: 2.7890x; 2.7890x over previous
//
#include <hip/hip_runtime.h>
#include <math.h>

// ---------------------------------------------------------------------------
// Shapes: B=16, T=1024, Din=64, D=512, Dff=2048, L=4, H=8, dh=64, TOP_K=32.
// ---------------------------------------------------------------------------

#define TILE 64

// EPI: 0 = none, 1 = +bias, 2 = +bias +exact GELU, 3 = +bias +pos_encoding
template<int EPI>
__global__ __launch_bounds__(256) void gemm_kernel(const float* __restrict__ A,
    const float* __restrict__ B, const float* __restrict__ bias,
    float* __restrict__ C, int M, int N, int K) {
  __shared__ float As[16][TILE + 1];   // [k][m]
  __shared__ float Bs[16][TILE + 1];   // [k][n]
  const int tid = threadIdx.x;
  const int tx = tid & 15, ty = tid >> 4;
  const int bn = blockIdx.x * TILE, bm = blockIdx.y * TILE;
  float acc[4][4] = {};
  for (int k0 = 0; k0 < K; k0 += 16) {
#pragma unroll
    for (int i = 0; i < 4; i++) {
      int idx = tid + i * 256;             // 0..1023
      int am = idx >> 4, ak = idx & 15;    // A tile 64x16
      As[ak][am] = A[(size_t)(bm + am) * K + k0 + ak];
      int bk = idx >> 6, bnn = idx & 63;   // B tile 16x64
      Bs[bk][bnn] = B[(size_t)(k0 + bk) * N + bn + bnn];
    }
    __syncthreads();
#pragma unroll
    for (int kk = 0; kk < 16; kk++) {
      float a[4], b[4];
#pragma unroll
      for (int i = 0; i < 4; i++) a[i] = As[kk][ty * 4 + i];
#pragma unroll
      for (int j = 0; j < 4; j++) b[j] = Bs[kk][tx * 4 + j];
#pragma unroll
      for (int i = 0; i < 4; i++)
#pragma unroll
        for (int j = 0; j < 4; j++) acc[i][j] = fmaf(a[i], b[j], acc[i][j]);
    }
    __syncthreads();
  }
#pragma unroll
  for (int i = 0; i < 4; i++) {
    int m = bm + ty * 4 + i;
    float4 o;
    float* op = &o.x;
#pragma unroll
    for (int j = 0; j < 4; j++) {
      int n = bn + tx * 4 + j;
      float vv = acc[i][j];
      if (EPI >= 1) vv += bias[n];
      if (EPI == 2) vv = 0.5f * vv * (1.0f + erff(vv * 0.70710678118654752f));
      if (EPI == 3) {
        int t = m & 1023;                         // row = b*T + t
        float fr = expf((float)(n & ~1) * (-9.210340371976184f / 512.0f));
        float ang = (float)t * fr;
        vv += (n & 1) ? cosf(ang) : sinf(ang);
      }
      op[j] = vv;
    }
    *(float4*)(&C[(size_t)m * N + bn + tx * 4]) = o;
  }
}

// ---------------------------------------------------------------------------
// Sparse top-32 attention, v2: LDS-staged K with XOR swizzle, 4 q-rows/wave,
// exact top-k via ballot radix-select, sparse PV from compacted candidates.
// ---------------------------------------------------------------------------

__device__ __forceinline__ unsigned f2o(float f) {   // monotone float->uint
  unsigned b = __float_as_uint(f);
  return (b & 0x80000000u) ? ~b : (b | 0x80000000u);
}
__device__ __forceinline__ float o2f(unsigned u) {   // inverse
  unsigned b = (u & 0x80000000u) ? (u & 0x7fffffffu) : ~u;
  return __uint_as_float(b);
}

__global__ __launch_bounds__(512, 4) void attn_kernel(const float* __restrict__ qa,
    const float* __restrict__ ka, const float* __restrict__ va,
    float* __restrict__ out) {
  // blockIdx.y = (b,h); blockIdx.x = 32-row t-chunk. 8 waves, 4 rows/wave.
  __shared__ __align__(16) float smem[16384 + 2048]; // ktile[256][64] | qlds[32][64]
  float* ktile = smem;
  float* qlds  = smem + 16384;
  float* cval  = smem;                    // overlay after QK^T: [32][96]
  int*   cidx  = (int*)smem + 32 * 96;    // [32][96]

  const int tid = threadIdx.x;
  const int wave = tid >> 6, lane = tid & 63;
  const int bh = blockIdx.y, b = bh >> 3, hh = bh & 7;
  const int t0 = blockIdx.x * 32;
  const float* kb = ka + (size_t)b * 1024 * 512 + hh * 64;
  const float* vb = va + (size_t)b * 1024 * 512 + hh * 64;

  // stage Q rows t0..t0+31 (scale by 1/sqrt(dh) here, once)
  {
    int row = tid >> 4, qq = tid & 15;
    float4 qv = *(const float4*)(qa + ((size_t)(b * 1024 + t0 + row)) * 512 + hh * 64 + qq * 4);
    qv.x *= 0.125f; qv.y *= 0.125f; qv.z *= 0.125f; qv.w *= 0.125f;
    *(float4*)(qlds + row * 64 + qq * 4) = qv;
  }

  float sc[4][16] = {};   // sc[r][tile*4+j] for s = (tile*4+j)*64 + lane

#pragma unroll
  for (int tile = 0; tile < 4; ++tile) {
    const float* kg = kb + (size_t)tile * 256 * 512;
#pragma unroll
    for (int i = 0; i < 8; ++i) {
      int idx = tid + i * 512;            // 256 rows x 16 quads
      int row = idx >> 4, qq = idx & 15;
      float4 kv = *(const float4*)(kg + (size_t)row * 512 + qq * 4);
      *(float4*)(ktile + row * 64 + ((qq ^ (row & 7)) * 4)) = kv; // swizzled
    }
    __syncthreads();
#pragma unroll 4
    for (int dq = 0; dq < 16; ++dq) {
      float4 qr[4];
#pragma unroll
      for (int r = 0; r < 4; ++r)
        qr[r] = *(const float4*)(qlds + (wave * 4 + r) * 64 + dq * 4); // broadcast
      const int swz = (dq ^ (lane & 7)) * 4;
#pragma unroll
      for (int j = 0; j < 4; ++j) {
        float4 kv = *(const float4*)(ktile + (j * 64 + lane) * 64 + swz);
#pragma unroll
        for (int r = 0; r < 4; ++r) {
          float a = sc[r][tile * 4 + j];
          a = fmaf(qr[r].x, kv.x, a); a = fmaf(qr[r].y, kv.y, a);
          a = fmaf(qr[r].z, kv.z, a); a = fmaf(qr[r].w, kv.w, a);
          sc[r][tile * 4 + j] = a;
        }
      }
    }
    __syncthreads();
  }
  // after this barrier ktile is dead -> cval/cidx overlay is safe (per-wave rows)

  unsigned uu[4][16];
#pragma unroll
  for (int r = 0; r < 4; ++r)
#pragma unroll
    for (int j = 0; j < 16; ++j) uu[r][j] = f2o(sc[r][j]);

#pragma unroll
  for (int r = 0; r < 4; ++r) {
    const int row = wave * 4 + r;
    // lane max + global max
    unsigned m = uu[r][0];
#pragma unroll
    for (int j = 1; j < 16; ++j) m = m > uu[r][j] ? m : uu[r][j];
    unsigned gm = m;
#pragma unroll
    for (int off = 32; off; off >>= 1) {
      unsigned o = __shfl_xor(gm, off);
      gm = gm > o ? gm : o;
    }
    // lambda: largest 16-bit-granular v with count(lane-maxima >= v) >= 32
    unsigned lam = 0;
    for (int bit = 31; bit >= 16; --bit) {
      unsigned tv = lam | (1u << bit);
      if (__popcll(__ballot(m >= tv)) >= 32) lam = tv;
    }
    // compact candidates (uu >= lam) into cval/cidx (cap 96)
    int base = 0;
#pragma unroll
    for (int j = 0; j < 16; ++j) {
      bool p = uu[r][j] >= lam;
      unsigned long long mk = __ballot(p);
      int pos = base + (int)__popcll(mk & ((1ull << lane) - 1ull));
      if (p && pos < 96) { cval[row * 96 + pos] = o2f(uu[r][j]); cidx[row * 96 + pos] = j * 64 + lane; }
      base += (int)__popcll(mk);
    }
    int C = base;
    unsigned kth = 0;
    if (C <= 96) {
      unsigned cu0 = (lane < C)      ? f2o(cval[row * 96 + lane])      : 0u;
      unsigned cu1 = (64 + lane < C) ? f2o(cval[row * 96 + 64 + lane]) : 0u;
      for (int bit = 31; bit >= 0; --bit) {
        unsigned tv = kth | (1u << bit);
        int c = (int)__popcll(__ballot(cu0 >= tv)) + (int)__popcll(__ballot(cu1 >= tv));
        if (c >= 32) kth = tv;
      }
    } else {
      // rare: exact descent over all 1024 values, then recompact kept only
      for (int bit = 31; bit >= 0; --bit) {
        unsigned tv = kth | (1u << bit);
        int pc = 0;
#pragma unroll
        for (int j = 0; j < 16; ++j) pc += (uu[r][j] >= tv) ? 1 : 0;
#pragma unroll
        for (int off = 32; off; off >>= 1) pc += __shfl_xor(pc, off);
        if (pc >= 32) kth = tv;
      }
      base = 0;
#pragma unroll
      for (int j = 0; j < 16; ++j) {
        bool p = uu[r][j] >= kth;
        unsigned long long mk = __ballot(p);
        int pos = base + (int)__popcll(mk & ((1ull << lane) - 1ull));
        if (p && pos < 96) { cval[row * 96 + pos] = o2f(uu[r][j]); cidx[row * 96 + pos] = j * 64 + lane; }
        base += (int)__popcll(mk);
      }
      C = base < 96 ? base : 96;
    }
    // softmax over kept (val >= kth) and writeback of e into cval
    float kth_f = o2f(kth), gm_f = o2f(gm);
    float e0 = 0.f, e1 = 0.f;
    if (lane < C)      { float vv = cval[row * 96 + lane];      if (vv >= kth_f) e0 = __expf(vv - gm_f); }
    if (64 + lane < C) { float vv = cval[row * 96 + 64 + lane]; if (vv >= kth_f) e1 = __expf(vv - gm_f); }
    float ps = e0 + e1;
#pragma unroll
    for (int off = 32; off; off >>= 1) ps += __shfl_xor(ps, off);
    cval[row * 96 + lane] = e0;
    if (lane < 32) cval[row * 96 + 64 + lane] = e1;
    // sparse PV: out[d=lane] = (1/ps) * sum_i e_i * V[idx_i][d]
    float acc = 0.f;
    for (int i = 0; i < C; ++i) {
      float ev = cval[row * 96 + i];
      int   si = cidx[row * 96 + i];
      acc = fmaf(ev, vb[(size_t)si * 512 + lane], acc);
    }
    out[((size_t)(b * 1024 + t0 + row)) * 512 + hh * 64 + lane] = acc * (1.f / ps);
  }
}

// h[row] = LayerNorm(h[row] + o[row]) * g + be   (wave per row, 4 rows/block)
__global__ __launch_bounds__(256) void resid_ln_kernel(float* __restrict__ h,
    const float* __restrict__ o, const float* __restrict__ g,
    const float* __restrict__ be) {
  const int wave = threadIdx.x >> 6, lane = threadIdx.x & 63;
  const size_t row = (size_t)blockIdx.x * 4 + wave;
  float* hr = h + row * 512;
  const float* orr = o + row * 512;
  float x[8]; float s = 0.f, s2 = 0.f;
#pragma unroll
  for (int j = 0; j < 8; j++) {
    float vv = hr[j * 64 + lane] + orr[j * 64 + lane];
    x[j] = vv; s += vv; s2 += vv * vv;
  }
#pragma unroll
  for (int off = 32; off; off >>= 1) { s += __shfl_xor(s, off); s2 += __shfl_xor(s2, off); }
  float mean = s * (1.f / 512.f);
  float var  = s2 * (1.f / 512.f) - mean * mean;
  float r = rsqrtf(var + 1e-5f);
#pragma unroll
  for (int j = 0; j < 8; j++) {
    int d = j * 64 + lane;
    hr[d] = (x[j] - mean) * r * g[d] + be[d];
  }
}

// final two-head readout on h[:, -1, :]
__global__ __launch_bounds__(256) void head_kernel(const float* __restrict__ h,
    const float* __restrict__ gm, const float* __restrict__ bm,
    const float* __restrict__ Wm, const float* __restrict__ cm,
    const float* __restrict__ gs, const float* __restrict__ bs,
    const float* __restrict__ Ws, const float* __restrict__ cs,
    float* __restrict__ out) {
  const int wave = threadIdx.x >> 6, lane = threadIdx.x & 63;
  const int b = blockIdx.x * 4 + wave;
  const float* hr = h + ((size_t)b * 1024 + 1023) * 512;
  float x[8]; float s = 0.f, s2 = 0.f;
#pragma unroll
  for (int j = 0; j < 8; j++) { float vv = hr[j * 64 + lane]; x[j] = vv; s += vv; s2 += vv * vv; }
#pragma unroll
  for (int off = 32; off; off >>= 1) { s += __shfl_xor(s, off); s2 += __shfl_xor(s2, off); }
  float mean = s * (1.f / 512.f);
  float var  = s2 * (1.f / 512.f) - mean * mean;
  float r = rsqrtf(var + 1e-5f);
  float am = 0.f, as = 0.f;
#pragma unroll
  for (int j = 0; j < 8; j++) {
    int d = j * 64 + lane;
    float n = (x[j] - mean) * r;
    am = fmaf(n * gm[d] + bm[d], Wm[d], am);
    as = fmaf(n * gs[d] + bs[d], Ws[d], as);
  }
#pragma unroll
  for (int off = 32; off; off >>= 1) { am += __shfl_xor(am, off); as += __shfl_xor(as, off); }
  if (lane == 0) {
    const double Z = 2.326347874040841;
    float mu  = am + cm[0];
    float scl = 1.f / (1.f + expf(-(as + cs[0])));   // * SCALE_MAX(=1)
    float esc = (float)(exp(-0.5 * Z * Z) / sqrt(2.0 * 3.14159265358979323846) / 0.01);
    out[b]      = mu;
    out[16 + b] = scl;
    out[32 + b] = mu + scl * (float)Z;
    out[48 + b] = mu + scl * esc;
  }
}

extern "C" void kernel_launch(void* const* d_in, const int* in_sizes, int n_in,
                              void* d_out, int out_size, void* d_ws, size_t ws_size,
                              hipStream_t stream) {
  const float* x    = (const float*)d_in[0];
  const float* W_in = (const float*)d_in[1];
  const float* b_in = (const float*)d_in[2];
  const float* Wq   = (const float*)d_in[3];
  const float* Wk   = (const float*)d_in[4];
  const float* Wv   = (const float*)d_in[5];
  const float* Wo   = (const float*)d_in[6];
  const float* bo   = (const float*)d_in[7];
  const float* W1   = (const float*)d_in[8];
  const float* b1   = (const float*)d_in[9];
  const float* W2   = (const float*)d_in[10];
  const float* b2   = (const float*)d_in[11];
  const float* g1   = (const float*)d_in[12];
  const float* be1  = (const float*)d_in[13];
  const float* g2   = (const float*)d_in[14];
  const float* be2  = (const float*)d_in[15];
  const float* gm   = (const float*)d_in[16];
  const float* bm   = (const float*)d_in[17];
  const float* Wm   = (const float*)d_in[18];
  const float* cm   = (const float*)d_in[19];
  const float* gs   = (const float*)d_in[20];
  const float* bs   = (const float*)d_in[21];
  const float* Ws   = (const float*)d_in[22];
  const float* cs   = (const float*)d_in[23];

  const int M = 16384, D = 512, DFF = 2048;
  float* ws = (float*)d_ws;
  float* h  = ws;                   // 16384x512
  float* bq = ws +  8388608;        // 16384x512
  float* bk = ws + 16777216;        // 16384x512
  float* bv = ws + 25165824;        // 16384x512
  float* ba = ws + 33554432;        // 16384x512
  float* bb = ws + 41943040;        // 16384x512
  float* ff = bq;                   // 16384x2048 spans bq..ba (contiguous)

  dim3 blk(256);
  dim3 gD(D / 64, M / 64);          // (8, 256)
  dim3 gF(DFF / 64, M / 64);        // (32, 256)

  // h = x @ W_in + b_in + pos_encoding
  gemm_kernel<3><<<gD, blk, 0, stream>>>(x, W_in, b_in, h, M, D, 64);

  for (int l = 0; l < 4; l++) {
    const float* wq = Wq + (size_t)l * D * D;
    const float* wk = Wk + (size_t)l * D * D;
    const float* wv = Wv + (size_t)l * D * D;
    const float* wo = Wo + (size_t)l * D * D;

    gemm_kernel<0><<<gD, blk, 0, stream>>>(h, wq, nullptr, bq, M, D, D);
    gemm_kernel<0><<<gD, blk, 0, stream>>>(h, wk, nullptr, bk, M, D, D);
    gemm_kernel<0><<<gD, blk, 0, stream>>>(h, wv, nullptr, bv, M, D, D);

    attn_kernel<<<dim3(32, 128), dim3(512), 0, stream>>>(bq, bk, bv, ba);

    gemm_kernel<1><<<gD, blk, 0, stream>>>(ba, wo, bo + (size_t)l * D, bq, M, D, D);
    resid_ln_kernel<<<dim3(4096), blk, 0, stream>>>(h, bq, g1 + (size_t)l * D, be1 + (size_t)l * D);

    gemm_kernel<2><<<gF, blk, 0, stream>>>(h, W1 + (size_t)l * D * DFF, b1 + (size_t)l * DFF, ff, M, DFF, D);
    gemm_kernel<1><<<gD, blk, 0, stream>>>(ff, W2 + (size_t)l * DFF * D, b2 + (size_t)l * D, bb, M, D, DFF);
    resid_ln_kernel<<<dim3(4096), blk, 0, stream>>>(h, bb, g2 + (size_t)l * D, be2 + (size_t)l * D);
  }

  head_kernel<<<dim3(4), blk, 0, stream>>>(h, gm, bm, Wm, cm, gs, bs, Ws, cs, (float*)d_out);
}

// Round 8
// 3721.806 us; speedup vs baseline: 7.2995x; 2.6173x over previous
//
#include <hip/hip_runtime.h>
#include <math.h>

// fp32 activations; weights split to hi/lo fp16 planes (w=hi+lo).
// GEMM = 3 MFMAs/fragment (hi*hi + lo*hi + hi*lo), fp32 accum => ~fp32 result.
// B=16,T=1024,Din=64,D=512,Dff=2048,L=4,H=8,dh=64,TOPK=32,M=16384.
// R5-R7 never compiled: container /tmp full (infra). Identical resubmit.

typedef unsigned int u32;
typedef __attribute__((ext_vector_type(8))) _Float16 f16x8;
typedef __attribute__((ext_vector_type(4))) float f32x4;

__device__ __forceinline__ void g2l16(const void* g, void* l) {
  __builtin_amdgcn_global_load_lds(
      (const __attribute__((address_space(1))) u32*)g,
      (__attribute__((address_space(3))) u32*)l, 16, 0, 0);
}

__global__ __launch_bounds__(256) void wprep_kernel(const float* __restrict__ src,
    unsigned short* __restrict__ dst_hi, unsigned short* __restrict__ dst_lo,
    int K, int N) {
  __shared__ float t[64][65];
  src    += (size_t)blockIdx.z * K * N;
  dst_hi += (size_t)blockIdx.z * K * N;
  dst_lo += (size_t)blockIdx.z * K * N;
  const int k0 = blockIdx.y * 64, n0 = blockIdx.x * 64;
#pragma unroll
  for (int i = 0; i < 16; i++) {
    int idx = threadIdx.x + i * 256;
    int kk = idx >> 6, nn = idx & 63;
    t[kk][nn] = src[(size_t)(k0 + kk) * N + n0 + nn];
  }
  __syncthreads();
#pragma unroll
  for (int i = 0; i < 16; i++) {
    int idx = threadIdx.x + i * 256;
    int nn = idx >> 6, kk = idx & 63;
    float w = t[kk][nn];
    _Float16 hi = (_Float16)w;
    _Float16 lo = (_Float16)(w - (float)hi);
    union { _Float16 h; unsigned short u; } a, b; a.h = hi; b.h = lo;
    dst_hi[(size_t)(n0 + nn) * K + k0 + kk] = a.u;
    dst_lo[(size_t)(n0 + nn) * K + k0 + kk] = b.u;
  }
}

__global__ __launch_bounds__(256) void gemm_split(const float* __restrict__ A,
    const unsigned short* __restrict__ Bhi, const unsigned short* __restrict__ Blo,
    const float* __restrict__ bias, float* __restrict__ C,
    int M, int N, int K, int ldb, int epi) {
  __shared__ float          As[128 * 64];
  __shared__ unsigned short BsH[128 * 64];
  __shared__ unsigned short BsL[128 * 64];
  const int tid = threadIdx.x;
  const int w = tid >> 6, l = tid & 63;
  const int wm = w >> 1, wn = w & 1;
  const int bm = blockIdx.y * 128, bn = blockIdx.x * 128;
  f32x4 acc[4][4] = {};

  for (int k0 = 0; k0 < K; k0 += 64) {
    if (k0) __syncthreads();
#pragma unroll
    for (int i = 0; i < 8; i++) {
      int cl = i * 256 + w * 64 + l;
      int row = cl >> 4, c = cl & 15;
      int col = (((c >> 1) ^ (row & 7)) * 8) + (c & 1) * 4;
      g2l16(A + (size_t)(bm + row) * K + k0 + col, As + (size_t)(i * 256 + w * 64) * 4);
    }
#pragma unroll
    for (int i = 0; i < 4; i++) {
      int cl = i * 256 + w * 64 + l;
      int row = cl >> 3, c = cl & 7;
      int col = ((c ^ (row & 7)) * 8);
      size_t src = (size_t)(bn + row) * ldb + k0 + col;
      g2l16(Bhi + src, BsH + (size_t)(i * 256 + w * 64) * 8);
      g2l16(Blo + src, BsL + (size_t)(i * 256 + w * 64) * 8);
    }
    __syncthreads();
#pragma unroll
    for (int kk = 0; kk < 2; kk++) {
      f16x8 ahi[4], alo[4], bhi[4], blo[4];
      const int c16 = kk * 4 + (l >> 4);
#pragma unroll
      for (int i = 0; i < 4; i++) {
        int ar = wm * 64 + i * 16 + (l & 15);
        const float* ap = &As[ar * 64 + ((c16 ^ (ar & 7)) * 8)];
        float4 a0 = *(const float4*)ap;
        float4 a1 = *(const float4*)(ap + 4);
        float av[8] = {a0.x, a0.y, a0.z, a0.w, a1.x, a1.y, a1.z, a1.w};
#pragma unroll
        for (int e = 0; e < 8; e++) {
          _Float16 hh = (_Float16)av[e];
          ahi[i][e] = hh;
          alo[i][e] = (_Float16)(av[e] - (float)hh);
        }
        int br = wn * 64 + i * 16 + (l & 15);
        bhi[i] = *(const f16x8*)&BsH[br * 64 + ((c16 ^ (br & 7)) * 8)];
        blo[i] = *(const f16x8*)&BsL[br * 64 + ((c16 ^ (br & 7)) * 8)];
      }
#pragma unroll
      for (int i = 0; i < 4; i++)
#pragma unroll
        for (int j = 0; j < 4; j++) {
          acc[i][j] = __builtin_amdgcn_mfma_f32_16x16x32_f16(ahi[i], bhi[j], acc[i][j], 0, 0, 0);
          acc[i][j] = __builtin_amdgcn_mfma_f32_16x16x32_f16(alo[i], bhi[j], acc[i][j], 0, 0, 0);
          acc[i][j] = __builtin_amdgcn_mfma_f32_16x16x32_f16(ahi[i], blo[j], acc[i][j], 0, 0, 0);
        }
    }
  }

  float bj[4], fr[4];
#pragma unroll
  for (int j = 0; j < 4; j++) {
    int col = bn + wn * 64 + j * 16 + (l & 15);
    bj[j] = (bias != nullptr) ? bias[col] : 0.f;
    fr[j] = (epi == 3) ? __expf((float)(col & ~1) * (-9.210340371976184f / 512.0f)) : 0.f;
  }
#pragma unroll
  for (int i = 0; i < 4; i++) {
#pragma unroll
    for (int e = 0; e < 4; e++) {
      int row = bm + wm * 64 + i * 16 + (l >> 4) * 4 + e;
#pragma unroll
      for (int j = 0; j < 4; j++) {
        int col = bn + wn * 64 + j * 16 + (l & 15);
        float v = acc[i][j][e] + bj[j];
        if (epi == 2) v = 0.5f * v * (1.0f + erff(v * 0.70710678118654752f));
        if (epi == 3) {
          float ang = (float)(row & 1023) * fr[j];
          v += (col & 1) ? cosf(ang) : sinf(ang);
        }
        if (epi == 4) v += C[(size_t)row * N + col];
        C[(size_t)row * N + col] = v;
      }
    }
  }
}

__device__ __forceinline__ unsigned f2o(float f) {
  unsigned b = __float_as_uint(f);
  return (b & 0x80000000u) ? ~b : (b | 0x80000000u);
}
__device__ __forceinline__ float o2f(unsigned u) {
  unsigned b = (u & 0x80000000u) ? (u & 0x7fffffffu) : ~u;
  return __uint_as_float(b);
}

__global__ __launch_bounds__(512, 4) void attn_kernel(float* __restrict__ qa,
    const float* __restrict__ ka, const float* __restrict__ va) {
  __shared__ __align__(16) float smem[16384 + 2048];
  float* ktile = smem;
  float* qlds  = smem + 16384;
  float* cval  = smem;
  int*   cidx  = (int*)smem + 32 * 96;

  const int tid = threadIdx.x;
  const int wave = tid >> 6, lane = tid & 63;
  const int bh = blockIdx.y, b = bh >> 3, hh = bh & 7;
  const int t0 = blockIdx.x * 32;
  const float* kb = ka + (size_t)b * 1024 * 512 + hh * 64;
  const float* vb = va + (size_t)b * 1024 * 512 + hh * 64;

  {
    int row = tid >> 4, qq = tid & 15;
    float4 qv = *(const float4*)(qa + ((size_t)(b * 1024 + t0 + row)) * 512 + hh * 64 + qq * 4);
    qv.x *= 0.125f; qv.y *= 0.125f; qv.z *= 0.125f; qv.w *= 0.125f;
    *(float4*)(qlds + row * 64 + qq * 4) = qv;
  }

  float sc[4][16] = {};

#pragma unroll
  for (int tile = 0; tile < 4; ++tile) {
    const float* kg = kb + (size_t)tile * 256 * 512;
#pragma unroll
    for (int i = 0; i < 8; ++i) {
      int idx = tid + i * 512;
      int row = idx >> 4, qq = idx & 15;
      float4 kv = *(const float4*)(kg + (size_t)row * 512 + qq * 4);
      *(float4*)(ktile + row * 64 + ((qq ^ (row & 7)) * 4)) = kv;
    }
    __syncthreads();
#pragma unroll 4
    for (int dq = 0; dq < 16; ++dq) {
      float4 qr[4];
#pragma unroll
      for (int r = 0; r < 4; ++r)
        qr[r] = *(const float4*)(qlds + (wave * 4 + r) * 64 + dq * 4);
      const int swz = (dq ^ (lane & 7)) * 4;
#pragma unroll
      for (int j = 0; j < 4; ++j) {
        float4 kv = *(const float4*)(ktile + (j * 64 + lane) * 64 + swz);
#pragma unroll
        for (int r = 0; r < 4; ++r) {
          float a = sc[r][tile * 4 + j];
          a = fmaf(qr[r].x, kv.x, a); a = fmaf(qr[r].y, kv.y, a);
          a = fmaf(qr[r].z, kv.z, a); a = fmaf(qr[r].w, kv.w, a);
          sc[r][tile * 4 + j] = a;
        }
      }
    }
    __syncthreads();
  }

  unsigned uu[4][16];
#pragma unroll
  for (int r = 0; r < 4; ++r)
#pragma unroll
    for (int j = 0; j < 16; ++j) uu[r][j] = f2o(sc[r][j]);

#pragma unroll
  for (int r = 0; r < 4; ++r) {
    const int row = wave * 4 + r;
    unsigned m = uu[r][0];
#pragma unroll
    for (int j = 1; j < 16; ++j) m = m > uu[r][j] ? m : uu[r][j];
    unsigned gm = m;
#pragma unroll
    for (int off = 32; off; off >>= 1) {
      unsigned o = __shfl_xor(gm, off);
      gm = gm > o ? gm : o;
    }
    unsigned lam = 0;
    for (int bit = 31; bit >= 16; --bit) {
      unsigned tv = lam | (1u << bit);
      if (__popcll(__ballot(m >= tv)) >= 32) lam = tv;
    }
    int base = 0;
#pragma unroll
    for (int j = 0; j < 16; ++j) {
      bool p = uu[r][j] >= lam;
      unsigned long long mk = __ballot(p);
      int pos = base + (int)__popcll(mk & ((1ull << lane) - 1ull));
      if (p && pos < 96) { cval[row * 96 + pos] = o2f(uu[r][j]); cidx[row * 96 + pos] = j * 64 + lane; }
      base += (int)__popcll(mk);
    }
    int C = base;
    unsigned kth = 0;
    if (C <= 96) {
      unsigned cu0 = (lane < C)      ? f2o(cval[row * 96 + lane])      : 0u;
      unsigned cu1 = (64 + lane < C) ? f2o(cval[row * 96 + 64 + lane]) : 0u;
      for (int bit = 31; bit >= 0; --bit) {
        unsigned tv = kth | (1u << bit);
        int c = (int)__popcll(__ballot(cu0 >= tv)) + (int)__popcll(__ballot(cu1 >= tv));
        if (c >= 32) kth = tv;
      }
    } else {
      for (int bit = 31; bit >= 0; --bit) {
        unsigned tv = kth | (1u << bit);
        int pc = 0;
#pragma unroll
        for (int j = 0; j < 16; ++j) pc += (uu[r][j] >= tv) ? 1 : 0;
#pragma unroll
        for (int off = 32; off; off >>= 1) pc += __shfl_xor(pc, off);
        if (pc >= 32) kth = tv;
      }
      base = 0;
#pragma unroll
      for (int j = 0; j < 16; ++j) {
        bool p = uu[r][j] >= kth;
        unsigned long long mk = __ballot(p);
        int pos = base + (int)__popcll(mk & ((1ull << lane) - 1ull));
        if (p && pos < 96) { cval[row * 96 + pos] = o2f(uu[r][j]); cidx[row * 96 + pos] = j * 64 + lane; }
        base += (int)__popcll(mk);
      }
      C = base < 96 ? base : 96;
    }
    float kth_f = o2f(kth), gm_f = o2f(gm);
    float e0 = 0.f, e1 = 0.f;
    if (lane < C)      { float vv = cval[row * 96 + lane];      if (vv >= kth_f) e0 = __expf(vv - gm_f); }
    if (64 + lane < C) { float vv = cval[row * 96 + 64 + lane]; if (vv >= kth_f) e1 = __expf(vv - gm_f); }
    float ps = e0 + e1;
#pragma unroll
    for (int off = 32; off; off >>= 1) ps += __shfl_xor(ps, off);
    cval[row * 96 + lane] = e0;
    if (lane < 32) cval[row * 96 + 64 + lane] = e1;
    float acc = 0.f;
    for (int i = 0; i < C; ++i) {
      float ev = cval[row * 96 + i];
      int   si = cidx[row * 96 + i];
      acc = fmaf(ev, vb[(size_t)si * 512 + lane], acc);
    }
    qa[((size_t)(b * 1024 + t0 + row)) * 512 + hh * 64 + lane] = acc * (1.f / ps);
  }
}

__global__ __launch_bounds__(256) void resid_ln_kernel(float* __restrict__ h,
    const float* __restrict__ o, const float* __restrict__ g,
    const float* __restrict__ be) {
  const int wave = threadIdx.x >> 6, lane = threadIdx.x & 63;
  const size_t row = (size_t)blockIdx.x * 4 + wave;
  float* hr = h + row * 512;
  const float* orr = o + row * 512;
  float x[8]; float s = 0.f, s2 = 0.f;
#pragma unroll
  for (int j = 0; j < 8; j++) {
    float vv = hr[j * 64 + lane] + orr[j * 64 + lane];
    x[j] = vv; s += vv; s2 += vv * vv;
  }
#pragma unroll
  for (int off = 32; off; off >>= 1) { s += __shfl_xor(s, off); s2 += __shfl_xor(s2, off); }
  float mean = s * (1.f / 512.f);
  float var  = s2 * (1.f / 512.f) - mean * mean;
  float r = rsqrtf(var + 1e-5f);
#pragma unroll
  for (int j = 0; j < 8; j++) {
    int d = j * 64 + lane;
    hr[d] = (x[j] - mean) * r * g[d] + be[d];
  }
}

__global__ __launch_bounds__(256) void head_kernel(const float* __restrict__ h,
    const float* __restrict__ gm, const float* __restrict__ bm,
    const float* __restrict__ Wm, const float* __restrict__ cm,
    const float* __restrict__ gs, const float* __restrict__ bs,
    const float* __restrict__ Ws, const float* __restrict__ cs,
    float* __restrict__ out) {
  const int wave = threadIdx.x >> 6, lane = threadIdx.x & 63;
  const int b = blockIdx.x * 4 + wave;
  const float* hr = h + ((size_t)b * 1024 + 1023) * 512;
  float x[8]; float s = 0.f, s2 = 0.f;
#pragma unroll
  for (int j = 0; j < 8; j++) { float vv = hr[j * 64 + lane]; x[j] = vv; s += vv; s2 += vv * vv; }
#pragma unroll
  for (int off = 32; off; off >>= 1) { s += __shfl_xor(s, off); s2 += __shfl_xor(s2, off); }
  float mean = s * (1.f / 512.f);
  float var  = s2 * (1.f / 512.f) - mean * mean;
  float r = rsqrtf(var + 1e-5f);
  float am = 0.f, as = 0.f;
#pragma unroll
  for (int j = 0; j < 8; j++) {
    int d = j * 64 + lane;
    float n = (x[j] - mean) * r;
    am = fmaf(n * gm[d] + bm[d], Wm[d], am);
    as = fmaf(n * gs[d] + bs[d], Ws[d], as);
  }
#pragma unroll
  for (int off = 32; off; off >>= 1) { am += __shfl_xor(am, off); as += __shfl_xor(as, off); }
  if (lane == 0) {
    const double Z = 2.326347874040841;
    float mu  = am + cm[0];
    float scl = 1.f / (1.f + expf(-(as + cs[0])));
    float esc = (float)(exp(-0.5 * Z * Z) / sqrt(2.0 * 3.14159265358979323846) / 0.01);
    out[b]      = mu;
    out[16 + b] = scl;
    out[32 + b] = mu + scl * (float)Z;
    out[48 + b] = mu + scl * esc;
  }
}

extern "C" void kernel_launch(void* const* d_in, const int* in_sizes, int n_in,
                              void* d_out, int out_size, void* d_ws, size_t ws_size,
                              hipStream_t stream) {
  const float* x    = (const float*)d_in[0];
  const float* W_in = (const float*)d_in[1];
  const float* b_in = (const float*)d_in[2];
  const float* Wq   = (const float*)d_in[3];
  const float* Wk   = (const float*)d_in[4];
  const float* Wv   = (const float*)d_in[5];
  const float* Wo   = (const float*)d_in[6];
  const float* bo   = (const float*)d_in[7];
  const float* W1   = (const float*)d_in[8];
  const float* b1   = (const float*)d_in[9];
  const float* W2   = (const float*)d_in[10];
  const float* b2   = (const float*)d_in[11];
  const float* g1   = (const float*)d_in[12];
  const float* be1  = (const float*)d_in[13];
  const float* g2   = (const float*)d_in[14];
  const float* be2  = (const float*)d_in[15];
  const float* gm   = (const float*)d_in[16];
  const float* bm   = (const float*)d_in[17];
  const float* Wm   = (const float*)d_in[18];
  const float* cm   = (const float*)d_in[19];
  const float* gs   = (const float*)d_in[20];
  const float* bs   = (const float*)d_in[21];
  const float* Ws   = (const float*)d_in[22];
  const float* cs   = (const float*)d_in[23];

  const int M = 16384, D = 512, DFF = 2048;
  float* ws = (float*)d_ws;
  float* h  = ws;
  float* q  = ws +  8388608;
  float* k  = ws + 16777216;
  float* v  = ws + 25165824;
  float* ff = k;
  unsigned short* wb = (unsigned short*)(ws + 33554432);
  unsigned short* WinH = wb;
  unsigned short* WinL = WinH + 32768;
  unsigned short* WqH  = WinL + 32768;
  unsigned short* WqL  = WqH  + 1048576;
  unsigned short* WkH  = WqL  + 1048576;
  unsigned short* WkL  = WkH  + 1048576;
  unsigned short* WvH  = WkL  + 1048576;
  unsigned short* WvL  = WvH  + 1048576;
  unsigned short* WoH  = WvL  + 1048576;
  unsigned short* WoL  = WoH  + 1048576;
  unsigned short* W1H  = WoL  + 1048576;
  unsigned short* W1L  = W1H  + 4194304;
  unsigned short* W2H  = W1L  + 4194304;
  unsigned short* W2L  = W2H  + 4194304;

  dim3 blk(256);

  wprep_kernel<<<dim3(8, 1, 1), blk, 0, stream>>>(W_in, WinH, WinL, 64, 512);
  wprep_kernel<<<dim3(8, 8, 4), blk, 0, stream>>>(Wq, WqH, WqL, 512, 512);
  wprep_kernel<<<dim3(8, 8, 4), blk, 0, stream>>>(Wk, WkH, WkL, 512, 512);
  wprep_kernel<<<dim3(8, 8, 4), blk, 0, stream>>>(Wv, WvH, WvL, 512, 512);
  wprep_kernel<<<dim3(8, 8, 4), blk, 0, stream>>>(Wo, WoH, WoL, 512, 512);
  wprep_kernel<<<dim3(32, 8, 4), blk, 0, stream>>>(W1, W1H, W1L, 512, 2048);
  wprep_kernel<<<dim3(8, 32, 4), blk, 0, stream>>>(W2, W2H, W2L, 2048, 512);

  dim3 gD(4, 128);
  dim3 gH(8, 128);

  gemm_split<<<gD, blk, 0, stream>>>(x, WinH, WinL, b_in, h, M, D, 64, 64, 3);

  for (int l = 0; l < 4; l++) {
    const size_t oD = (size_t)l * D * D;
    const size_t oF = (size_t)l * D * DFF;

    gemm_split<<<gD, blk, 0, stream>>>(h, WqH + oD, WqL + oD, nullptr, q, M, D, D, D, 1);
    gemm_split<<<gD, blk, 0, stream>>>(h, WkH + oD, WkL + oD, nullptr, k, M, D, D, D, 1);
    gemm_split<<<gD, blk, 0, stream>>>(h, WvH + oD, WvL + oD, nullptr, v, M, D, D, D, 1);

    attn_kernel<<<dim3(32, 128), dim3(512), 0, stream>>>(q, k, v);

    gemm_split<<<gD, blk, 0, stream>>>(q, WoH + oD, WoL + oD, bo + (size_t)l * D, k, M, D, D, D, 1);
    resid_ln_kernel<<<dim3(4096), blk, 0, stream>>>(h, k, g1 + (size_t)l * D, be1 + (size_t)l * D);

    gemm_split<<<gH, blk, 0, stream>>>(h, W1H + oF, W1L + oF, b1 + (size_t)l * DFF, ff, M, 1024, D, D, 2);
    gemm_split<<<gD, blk, 0, stream>>>(ff, W2H + oF, W2L + oF, nullptr, q, M, D, 1024, DFF, 1);
    gemm_split<<<gH, blk, 0, stream>>>(h, W1H + oF + 1024 * (size_t)D, W1L + oF + 1024 * (size_t)D,
                                       b1 + (size_t)l * DFF + 1024, ff, M, 1024, D, D, 2);
    gemm_split<<<gD, blk, 0, stream>>>(ff, W2H + oF + 1024, W2L + oF + 1024,
                                       b2 + (size_t)l * D, q, M, D, 1024, DFF, 4);

    resid_ln_kernel<<<dim3(4096), blk, 0, stream>>>(h, q, g2 + (size_t)l * D, be2 + (size_t)l * D);
  }

  head_kernel<<<dim3(4), blk, 0, stream>>>(h, gm, bm, Wm, cm, gs, bs, Ws, cs, (float*)d_out);
}

// Round 9
// 3273.871 us; speedup vs baseline: 8.2982x; 1.1368x over previous
//
#include <hip/hip_runtime.h>
#include <math.h>

// fp32 activations; weights + Q/K split to hi/lo fp16 planes (w=hi+lo).
// GEMM + attn QK^T = 3 MFMAs/fragment (hi*hi + lo*hi + hi*lo), fp32 accum.
// B=16,T=1024,Din=64,D=512,Dff=2048,L=4,H=8,dh=64,TOPK=32,M=16384.
// R9: attn QK^T moved to MFMA (epi5 emits head-separated Q/K hi/lo planes);
// per-layer weight prep (rotating 12.6MB buffer) to fit ws.

typedef unsigned int u32;
typedef __attribute__((ext_vector_type(8))) _Float16 f16x8;
typedef __attribute__((ext_vector_type(4))) float f32x4;

__device__ __forceinline__ void g2l16(const void* g, void* l) {
  __builtin_amdgcn_global_load_lds(
      (const __attribute__((address_space(1))) u32*)g,
      (__attribute__((address_space(3))) u32*)l, 16, 0, 0);
}

__global__ __launch_bounds__(256) void wprep_kernel(const float* __restrict__ src,
    unsigned short* __restrict__ dst_hi, unsigned short* __restrict__ dst_lo,
    int K, int N) {
  __shared__ float t[64][65];
  const int k0 = blockIdx.y * 64, n0 = blockIdx.x * 64;
#pragma unroll
  for (int i = 0; i < 16; i++) {
    int idx = threadIdx.x + i * 256;
    int kk = idx >> 6, nn = idx & 63;
    t[kk][nn] = src[(size_t)(k0 + kk) * N + n0 + nn];
  }
  __syncthreads();
#pragma unroll
  for (int i = 0; i < 16; i++) {
    int idx = threadIdx.x + i * 256;
    int nn = idx >> 6, kk = idx & 63;
    float w = t[kk][nn];
    _Float16 hi = (_Float16)w;
    _Float16 lo = (_Float16)(w - (float)hi);
    union { _Float16 h; unsigned short u; } a, b; a.h = hi; b.h = lo;
    dst_hi[(size_t)(n0 + nn) * K + k0 + kk] = a.u;
    dst_lo[(size_t)(n0 + nn) * K + k0 + kk] = b.u;
  }
}

// epi: 1 +bias(null ok)->C, 2 +bias+GELU->C, 3 +bias+posenc->C, 4 C+=acc+bias,
//      5 -> head-separated hi/lo fp16 planes Ph/Pl ([b][h][t][64])
__global__ __launch_bounds__(256) void gemm_split(const float* __restrict__ A,
    const unsigned short* __restrict__ Bhi, const unsigned short* __restrict__ Blo,
    const float* __restrict__ bias, float* __restrict__ C,
    unsigned short* __restrict__ Ph, unsigned short* __restrict__ Pl,
    int M, int N, int K, int ldb, int epi) {
  __shared__ float          As[128 * 64];
  __shared__ unsigned short BsH[128 * 64];
  __shared__ unsigned short BsL[128 * 64];
  const int tid = threadIdx.x;
  const int w = tid >> 6, l = tid & 63;
  const int wm = w >> 1, wn = w & 1;
  const int bm = blockIdx.y * 128, bn = blockIdx.x * 128;
  f32x4 acc[4][4] = {};

  for (int k0 = 0; k0 < K; k0 += 64) {
    if (k0) __syncthreads();
#pragma unroll
    for (int i = 0; i < 8; i++) {
      int cl = i * 256 + w * 64 + l;
      int row = cl >> 4, c = cl & 15;
      int col = (((c >> 1) ^ (row & 7)) * 8) + (c & 1) * 4;
      g2l16(A + (size_t)(bm + row) * K + k0 + col, As + (size_t)(i * 256 + w * 64) * 4);
    }
#pragma unroll
    for (int i = 0; i < 4; i++) {
      int cl = i * 256 + w * 64 + l;
      int row = cl >> 3, c = cl & 7;
      int col = ((c ^ (row & 7)) * 8);
      size_t src = (size_t)(bn + row) * ldb + k0 + col;
      g2l16(Bhi + src, BsH + (size_t)(i * 256 + w * 64) * 8);
      g2l16(Blo + src, BsL + (size_t)(i * 256 + w * 64) * 8);
    }
    __syncthreads();
#pragma unroll
    for (int kk = 0; kk < 2; kk++) {
      f16x8 ahi[4], alo[4], bhi[4], blo[4];
      const int c16 = kk * 4 + (l >> 4);
#pragma unroll
      for (int i = 0; i < 4; i++) {
        int ar = wm * 64 + i * 16 + (l & 15);
        const float* ap = &As[ar * 64 + ((c16 ^ (ar & 7)) * 8)];
        float4 a0 = *(const float4*)ap;
        float4 a1 = *(const float4*)(ap + 4);
        float av[8] = {a0.x, a0.y, a0.z, a0.w, a1.x, a1.y, a1.z, a1.w};
#pragma unroll
        for (int e = 0; e < 8; e++) {
          _Float16 hh = (_Float16)av[e];
          ahi[i][e] = hh;
          alo[i][e] = (_Float16)(av[e] - (float)hh);
        }
        int br = wn * 64 + i * 16 + (l & 15);
        bhi[i] = *(const f16x8*)&BsH[br * 64 + ((c16 ^ (br & 7)) * 8)];
        blo[i] = *(const f16x8*)&BsL[br * 64 + ((c16 ^ (br & 7)) * 8)];
      }
#pragma unroll
      for (int i = 0; i < 4; i++)
#pragma unroll
        for (int j = 0; j < 4; j++) {
          acc[i][j] = __builtin_amdgcn_mfma_f32_16x16x32_f16(ahi[i], bhi[j], acc[i][j], 0, 0, 0);
          acc[i][j] = __builtin_amdgcn_mfma_f32_16x16x32_f16(alo[i], bhi[j], acc[i][j], 0, 0, 0);
          acc[i][j] = __builtin_amdgcn_mfma_f32_16x16x32_f16(ahi[i], blo[j], acc[i][j], 0, 0, 0);
        }
    }
  }

  if (epi == 5) {
#pragma unroll
    for (int i = 0; i < 4; i++)
#pragma unroll
      for (int e = 0; e < 4; e++) {
        int row = bm + wm * 64 + i * 16 + (l >> 4) * 4 + e;
#pragma unroll
        for (int j = 0; j < 4; j++) {
          int col = bn + wn * 64 + j * 16 + (l & 15);
          float vv = acc[i][j][e];
          _Float16 hi = (_Float16)vv;
          _Float16 lo = (_Float16)(vv - (float)hi);
          union { _Float16 h; unsigned short u; } a, b; a.h = hi; b.h = lo;
          size_t off = (size_t)(row >> 10) * 524288 + (size_t)(col >> 6) * 65536
                     + (size_t)(row & 1023) * 64 + (col & 63);
          Ph[off] = a.u; Pl[off] = b.u;
        }
      }
    return;
  }

  float bj[4], fr[4];
#pragma unroll
  for (int j = 0; j < 4; j++) {
    int col = bn + wn * 64 + j * 16 + (l & 15);
    bj[j] = (bias != nullptr) ? bias[col] : 0.f;
    fr[j] = (epi == 3) ? __expf((float)(col & ~1) * (-9.210340371976184f / 512.0f)) : 0.f;
  }
#pragma unroll
  for (int i = 0; i < 4; i++) {
#pragma unroll
    for (int e = 0; e < 4; e++) {
      int row = bm + wm * 64 + i * 16 + (l >> 4) * 4 + e;
#pragma unroll
      for (int j = 0; j < 4; j++) {
        int col = bn + wn * 64 + j * 16 + (l & 15);
        float v = acc[i][j][e] + bj[j];
        if (epi == 2) v = 0.5f * v * (1.0f + erff(v * 0.70710678118654752f));
        if (epi == 3) {
          float ang = (float)(row & 1023) * fr[j];
          v += (col & 1) ? cosf(ang) : sinf(ang);
        }
        if (epi == 4) v += C[(size_t)row * N + col];
        C[(size_t)row * N + col] = v;
      }
    }
  }
}

__device__ __forceinline__ unsigned f2o(float f) {
  unsigned b = __float_as_uint(f);
  return (b & 0x80000000u) ? ~b : (b | 0x80000000u);
}
__device__ __forceinline__ float o2f(unsigned u) {
  unsigned b = (u & 0x80000000u) ? (u & 0x7fffffffu) : ~u;
  return __uint_as_float(b);
}

// 8 waves, 32 q-rows/block. QK^T via split-fp16 MFMA; S redistributed through
// stride-33 LDS; top-k/softmax/PV identical to the R8-verified path.
__global__ __launch_bounds__(512, 4) void attn_kernel(
    const unsigned short* __restrict__ qh, const unsigned short* __restrict__ ql,
    const unsigned short* __restrict__ kh, const unsigned short* __restrict__ kl,
    const float* __restrict__ va, float* __restrict__ ao) {
  __shared__ __align__(16) float smem[14464];
  unsigned short* Qhs = (unsigned short*)smem;    // [32][64] fp16
  unsigned short* Qls = Qhs + 2048;
  unsigned short* Khs = Qhs + 4096;               // [128][64] fp16
  unsigned short* Kls = Qhs + 12288;
  float* S    = smem + 10240;                     // [128][33] fp32
  float* cval = smem + 2048;                      // overlay on Khl: [32][96]
  int*   cidx = (int*)smem + 5120;                // [32][96]

  const int tid = threadIdx.x;
  const int wave = tid >> 6, lane = tid & 63;
  const int bh = blockIdx.y, b = bh >> 3, hh = bh & 7;
  const int t0 = blockIdx.x * 32;
  const size_t hoff = (size_t)bh * 65536;
  const float* vb = va + (size_t)b * 524288 + hh * 64;

  {  // stage Q (hi/lo), chunk-swizzled source -> linear LDS
    int plane = tid >> 8, cl = tid & 255;
    int row = cl >> 3, c = cl & 7;
    size_t src = hoff + (size_t)(t0 + row) * 64 + ((c ^ (row & 7)) * 8);
    g2l16((plane ? ql : qh) + src, (plane ? Qls : Qhs) + cl * 8);
  }

  float sc[4][16];

  for (int kt = 0; kt < 8; ++kt) {
#pragma unroll
    for (int i = 0; i < 2; ++i) {   // stage K tile (128 rows, hi+lo)
      int cl = tid + i * 512;
      int row = cl >> 3, c = cl & 7;
      size_t src = hoff + (size_t)(kt * 128 + row) * 64 + ((c ^ (row & 7)) * 8);
      g2l16(kh + src, Khs + cl * 8);
      g2l16(kl + src, Kls + cl * 8);
    }
    __syncthreads();

    f32x4 a0 = {}, a1 = {};
#pragma unroll
    for (int ks = 0; ks < 2; ++ks) {
      int c = (lane >> 4) + ks * 4;
      int kr = wave * 16 + (lane & 15);
      int ko = kr * 64 + ((c ^ (kr & 7)) * 8);
      f16x8 kfh = *(const f16x8*)&Khs[ko];
      f16x8 kfl = *(const f16x8*)&Kls[ko];
      int q0 = lane & 15;
      int o0 = q0 * 64 + ((c ^ (q0 & 7)) * 8);
      f16x8 qf0h = *(const f16x8*)&Qhs[o0];
      f16x8 qf0l = *(const f16x8*)&Qls[o0];
      int q1 = 16 + (lane & 15);
      int o1 = q1 * 64 + ((c ^ (q1 & 7)) * 8);
      f16x8 qf1h = *(const f16x8*)&Qhs[o1];
      f16x8 qf1l = *(const f16x8*)&Qls[o1];
      a0 = __builtin_amdgcn_mfma_f32_16x16x32_f16(kfh, qf0h, a0, 0, 0, 0);
      a0 = __builtin_amdgcn_mfma_f32_16x16x32_f16(kfl, qf0h, a0, 0, 0, 0);
      a0 = __builtin_amdgcn_mfma_f32_16x16x32_f16(kfh, qf0l, a0, 0, 0, 0);
      a1 = __builtin_amdgcn_mfma_f32_16x16x32_f16(kfh, qf1h, a1, 0, 0, 0);
      a1 = __builtin_amdgcn_mfma_f32_16x16x32_f16(kfl, qf1h, a1, 0, 0, 0);
      a1 = __builtin_amdgcn_mfma_f32_16x16x32_f16(kfh, qf1l, a1, 0, 0, 0);
    }
#pragma unroll
    for (int e = 0; e < 4; ++e) {   // D: row(s)=(lane>>4)*4+e, col(q)=lane&15
      int srow = wave * 16 + (lane >> 4) * 4 + e;
      S[srow * 33 + (lane & 15)]      = a0[e];
      S[srow * 33 + 16 + (lane & 15)] = a1[e];
    }
    __syncthreads();
#pragma unroll
    for (int r = 0; r < 4; ++r) {   // redistribute: s = (kt*2+j2)*64 + lane
      int qr = wave * 4 + r;
      sc[r][kt * 2]     = S[lane * 33 + qr] * 0.125f;
      sc[r][kt * 2 + 1] = S[(64 + lane) * 33 + qr] * 0.125f;
    }
    __syncthreads();
  }

  unsigned uu[4][16];
#pragma unroll
  for (int r = 0; r < 4; ++r)
#pragma unroll
    for (int j = 0; j < 16; ++j) uu[r][j] = f2o(sc[r][j]);

#pragma unroll
  for (int r = 0; r < 4; ++r) {
    const int row = wave * 4 + r;
    unsigned m = uu[r][0];
#pragma unroll
    for (int j = 1; j < 16; ++j) m = m > uu[r][j] ? m : uu[r][j];
    unsigned gm = m;
#pragma unroll
    for (int off = 32; off; off >>= 1) {
      unsigned o = __shfl_xor(gm, off);
      gm = gm > o ? gm : o;
    }
    unsigned lam = 0;
    for (int bit = 31; bit >= 16; --bit) {
      unsigned tv = lam | (1u << bit);
      if (__popcll(__ballot(m >= tv)) >= 32) lam = tv;
    }
    int base = 0;
#pragma unroll
    for (int j = 0; j < 16; ++j) {
      bool p = uu[r][j] >= lam;
      unsigned long long mk = __ballot(p);
      int pos = base + (int)__popcll(mk & ((1ull << lane) - 1ull));
      if (p && pos < 96) { cval[row * 96 + pos] = o2f(uu[r][j]); cidx[row * 96 + pos] = j * 64 + lane; }
      base += (int)__popcll(mk);
    }
    int C = base;
    unsigned kth = 0;
    if (C <= 96) {
      unsigned cu0 = (lane < C)      ? f2o(cval[row * 96 + lane])      : 0u;
      unsigned cu1 = (64 + lane < C) ? f2o(cval[row * 96 + 64 + lane]) : 0u;
      for (int bit = 31; bit >= 0; --bit) {
        unsigned tv = kth | (1u << bit);
        int c = (int)__popcll(__ballot(cu0 >= tv)) + (int)__popcll(__ballot(cu1 >= tv));
        if (c >= 32) kth = tv;
      }
    } else {
      for (int bit = 31; bit >= 0; --bit) {
        unsigned tv = kth | (1u << bit);
        int pc = 0;
#pragma unroll
        for (int j = 0; j < 16; ++j) pc += (uu[r][j] >= tv) ? 1 : 0;
#pragma unroll
        for (int off = 32; off; off >>= 1) pc += __shfl_xor(pc, off);
        if (pc >= 32) kth = tv;
      }
      base = 0;
#pragma unroll
      for (int j = 0; j < 16; ++j) {
        bool p = uu[r][j] >= kth;
        unsigned long long mk = __ballot(p);
        int pos = base + (int)__popcll(mk & ((1ull << lane) - 1ull));
        if (p && pos < 96) { cval[row * 96 + pos] = o2f(uu[r][j]); cidx[row * 96 + pos] = j * 64 + lane; }
        base += (int)__popcll(mk);
      }
      C = base < 96 ? base : 96;
    }
    float kth_f = o2f(kth), gm_f = o2f(gm);
    float e0 = 0.f, e1 = 0.f;
    if (lane < C)      { float vv = cval[row * 96 + lane];      if (vv >= kth_f) e0 = __expf(vv - gm_f); }
    if (64 + lane < C) { float vv = cval[row * 96 + 64 + lane]; if (vv >= kth_f) e1 = __expf(vv - gm_f); }
    float ps = e0 + e1;
#pragma unroll
    for (int off = 32; off; off >>= 1) ps += __shfl_xor(ps, off);
    cval[row * 96 + lane] = e0;
    if (lane < 32) cval[row * 96 + 64 + lane] = e1;
    float acc = 0.f;
    for (int i = 0; i < C; ++i) {
      float ev = cval[row * 96 + i];
      int   si = cidx[row * 96 + i];
      acc = fmaf(ev, vb[(size_t)si * 512 + lane], acc);
    }
    ao[((size_t)(b * 1024 + t0 + row)) * 512 + hh * 64 + lane] = acc * (1.f / ps);
  }
}

__global__ __launch_bounds__(256) void resid_ln_kernel(float* __restrict__ h,
    const float* __restrict__ o, const float* __restrict__ g,
    const float* __restrict__ be) {
  const int wave = threadIdx.x >> 6, lane = threadIdx.x & 63;
  const size_t row = (size_t)blockIdx.x * 4 + wave;
  float* hr = h + row * 512;
  const float* orr = o + row * 512;
  float x[8]; float s = 0.f, s2 = 0.f;
#pragma unroll
  for (int j = 0; j < 8; j++) {
    float vv = hr[j * 64 + lane] + orr[j * 64 + lane];
    x[j] = vv; s += vv; s2 += vv * vv;
  }
#pragma unroll
  for (int off = 32; off; off >>= 1) { s += __shfl_xor(s, off); s2 += __shfl_xor(s2, off); }
  float mean = s * (1.f / 512.f);
  float var  = s2 * (1.f / 512.f) - mean * mean;
  float r = rsqrtf(var + 1e-5f);
#pragma unroll
  for (int j = 0; j < 8; j++) {
    int d = j * 64 + lane;
    hr[d] = (x[j] - mean) * r * g[d] + be[d];
  }
}

__global__ __launch_bounds__(256) void head_kernel(const float* __restrict__ h,
    const float* __restrict__ gm, const float* __restrict__ bm,
    const float* __restrict__ Wm, const float* __restrict__ cm,
    const float* __restrict__ gs, const float* __restrict__ bs,
    const float* __restrict__ Ws, const float* __restrict__ cs,
    float* __restrict__ out) {
  const int wave = threadIdx.x >> 6, lane = threadIdx.x & 63;
  const int b = blockIdx.x * 4 + wave;
  const float* hr = h + ((size_t)b * 1024 + 1023) * 512;
  float x[8]; float s = 0.f, s2 = 0.f;
#pragma unroll
  for (int j = 0; j < 8; j++) { float vv = hr[j * 64 + lane]; x[j] = vv; s += vv; s2 += vv * vv; }
#pragma unroll
  for (int off = 32; off; off >>= 1) { s += __shfl_xor(s, off); s2 += __shfl_xor(s2, off); }
  float mean = s * (1.f / 512.f);
  float var  = s2 * (1.f / 512.f) - mean * mean;
  float r = rsqrtf(var + 1e-5f);
  float am = 0.f, as = 0.f;
#pragma unroll
  for (int j = 0; j < 8; j++) {
    int d = j * 64 + lane;
    float n = (x[j] - mean) * r;
    am = fmaf(n * gm[d] + bm[d], Wm[d], am);
    as = fmaf(n * gs[d] + bs[d], Ws[d], as);
  }
#pragma unroll
  for (int off = 32; off; off >>= 1) { am += __shfl_xor(am, off); as += __shfl_xor(as, off); }
  if (lane == 0) {
    const double Z = 2.326347874040841;
    float mu  = am + cm[0];
    float scl = 1.f / (1.f + expf(-(as + cs[0])));
    float esc = (float)(exp(-0.5 * Z * Z) / sqrt(2.0 * 3.14159265358979323846) / 0.01);
    out[b]      = mu;
    out[16 + b] = scl;
    out[32 + b] = mu + scl * (float)Z;
    out[48 + b] = mu + scl * esc;
  }
}

extern "C" void kernel_launch(void* const* d_in, const int* in_sizes, int n_in,
                              void* d_out, int out_size, void* d_ws, size_t ws_size,
                              hipStream_t stream) {
  const float* x    = (const float*)d_in[0];
  const float* W_in = (const float*)d_in[1];
  const float* b_in = (const float*)d_in[2];
  const float* Wq   = (const float*)d_in[3];
  const float* Wk   = (const float*)d_in[4];
  const float* Wv   = (const float*)d_in[5];
  const float* Wo   = (const float*)d_in[6];
  const float* bo   = (const float*)d_in[7];
  const float* W1   = (const float*)d_in[8];
  const float* b1   = (const float*)d_in[9];
  const float* W2   = (const float*)d_in[10];
  const float* b2   = (const float*)d_in[11];
  const float* g1   = (const float*)d_in[12];
  const float* be1  = (const float*)d_in[13];
  const float* g2   = (const float*)d_in[14];
  const float* be2  = (const float*)d_in[15];
  const float* gm   = (const float*)d_in[16];
  const float* bm   = (const float*)d_in[17];
  const float* Wm   = (const float*)d_in[18];
  const float* cm   = (const float*)d_in[19];
  const float* gs   = (const float*)d_in[20];
  const float* bs   = (const float*)d_in[21];
  const float* Ws   = (const float*)d_in[22];
  const float* cs   = (const float*)d_in[23];

  const int M = 16384, D = 512, DFF = 2048;
  float* ws = (float*)d_ws;
  float* h   = ws;                                   // [16384][512] fp32
  unsigned short* qhp = (unsigned short*)(ws + 8388608);   // [128][1024][64] hi
  unsigned short* qlp = qhp + 8388608;                     // lo
  unsigned short* khp = (unsigned short*)(ws + 16777216);
  unsigned short* klp = khp + 8388608;
  float* v   = ws + 25165824;                        // V fp32 / Wo-out
  float* ao  = ws + 33554432;                        // attn-out / FFN2-out
  float* ff  = ws + 8388608;                         // FFN half [16384][1024]
  unsigned short* wl = (unsigned short*)(ws + 41943040);   // per-layer planes
  unsigned short* WqH = wl,            *WqL = wl + 262144;
  unsigned short* WkH = wl + 524288,   *WkL = wl + 786432;
  unsigned short* WvH = wl + 1048576,  *WvL = wl + 1310720;
  unsigned short* WoH = wl + 1572864,  *WoL = wl + 1835008;
  unsigned short* W1H = wl + 2097152,  *W1L = wl + 3145728;
  unsigned short* W2H = wl + 4194304,  *W2L = wl + 5242880;
  unsigned short* WinH = (unsigned short*)(ws + 45088768);
  unsigned short* WinL = WinH + 32768;

  dim3 blk(256);
  dim3 gD(4, 128);    // N=512
  dim3 gH(8, 128);    // N=1024 (FFN1 half)

  wprep_kernel<<<dim3(8, 1, 1), blk, 0, stream>>>(W_in, WinH, WinL, 64, 512);
  gemm_split<<<gD, blk, 0, stream>>>(x, WinH, WinL, b_in, h, nullptr, nullptr, M, D, 64, 64, 3);

  for (int l = 0; l < 4; l++) {
    const float* wq = Wq + (size_t)l * 262144;
    const float* wk = Wk + (size_t)l * 262144;
    const float* wv = Wv + (size_t)l * 262144;
    const float* wo = Wo + (size_t)l * 262144;
    const float* w1 = W1 + (size_t)l * 1048576;
    const float* w2 = W2 + (size_t)l * 1048576;

    wprep_kernel<<<dim3(8, 8, 1), blk, 0, stream>>>(wq, WqH, WqL, 512, 512);
    wprep_kernel<<<dim3(8, 8, 1), blk, 0, stream>>>(wk, WkH, WkL, 512, 512);
    wprep_kernel<<<dim3(8, 8, 1), blk, 0, stream>>>(wv, WvH, WvL, 512, 512);
    wprep_kernel<<<dim3(8, 8, 1), blk, 0, stream>>>(wo, WoH, WoL, 512, 512);
    wprep_kernel<<<dim3(32, 8, 1), blk, 0, stream>>>(w1, W1H, W1L, 512, 2048);
    wprep_kernel<<<dim3(8, 32, 1), blk, 0, stream>>>(w2, W2H, W2L, 2048, 512);

    gemm_split<<<gD, blk, 0, stream>>>(h, WqH, WqL, nullptr, nullptr, qhp, qlp, M, D, D, D, 5);
    gemm_split<<<gD, blk, 0, stream>>>(h, WkH, WkL, nullptr, nullptr, khp, klp, M, D, D, D, 5);
    gemm_split<<<gD, blk, 0, stream>>>(h, WvH, WvL, nullptr, v, nullptr, nullptr, M, D, D, D, 1);

    attn_kernel<<<dim3(32, 128), dim3(512), 0, stream>>>(qhp, qlp, khp, klp, v, ao);

    gemm_split<<<gD, blk, 0, stream>>>(ao, WoH, WoL, bo + (size_t)l * D, v, nullptr, nullptr, M, D, D, D, 1);
    resid_ln_kernel<<<dim3(4096), blk, 0, stream>>>(h, v, g1 + (size_t)l * D, be1 + (size_t)l * D);

    gemm_split<<<gH, blk, 0, stream>>>(h, W1H, W1L, b1 + (size_t)l * DFF, ff, nullptr, nullptr, M, 1024, D, D, 2);
    gemm_split<<<gD, blk, 0, stream>>>(ff, W2H, W2L, nullptr, ao, nullptr, nullptr, M, D, 1024, DFF, 1);
    gemm_split<<<gH, blk, 0, stream>>>(h, W1H + 524288, W1L + 524288,
                                       b1 + (size_t)l * DFF + 1024, ff, nullptr, nullptr, M, 1024, D, D, 2);
    gemm_split<<<gD, blk, 0, stream>>>(ff, W2H + 1024, W2L + 1024,
                                       b2 + (size_t)l * D, ao, nullptr, nullptr, M, D, 1024, DFF, 4);

    resid_ln_kernel<<<dim3(4096), blk, 0, stream>>>(h, ao, g2 + (size_t)l * D, be2 + (size_t)l * D);
  }

  head_kernel<<<dim3(4), blk, 0, stream>>>(h, gm, bm, Wm, cm, gs, bs, Ws, cs, (float*)d_out);
}

// Round 10
// 3196.512 us; speedup vs baseline: 8.4991x; 1.0242x over previous
//
#include <hip/hip_runtime.h>
#include <math.h>

// fp32 activations; weights + Q/K split to hi/lo fp16 planes (w=hi+lo).
// GEMM + attn QK^T = 3 MFMAs/fragment (hi*hi + lo*hi + hi*lo), fp32 accum.
// B=16,T=1024,Din=64,D=512,Dff=2048,L=4,H=8,dh=64,TOPK=32,M=16384.
// R10: attn grid XCD-locality swizzle (all 32 t-chunks of a (b,h) on one XCD
// -> V+K L2-resident, kills the 268MB/dispatch PV gather overfetch);
// wprep4 fuses the 4 DxD weight preps per layer into one launch.

typedef unsigned int u32;
typedef __attribute__((ext_vector_type(8))) _Float16 f16x8;
typedef __attribute__((ext_vector_type(4))) float f32x4;

__device__ __forceinline__ void g2l16(const void* g, void* l) {
  __builtin_amdgcn_global_load_lds(
      (const __attribute__((address_space(1))) u32*)g,
      (__attribute__((address_space(3))) u32*)l, 16, 0, 0);
}

__device__ __forceinline__ void wsplit(float w, unsigned short* ph, unsigned short* pl) {
  _Float16 hi = (_Float16)w;
  _Float16 lo = (_Float16)(w - (float)hi);
  union { _Float16 h; unsigned short u; } a, b; a.h = hi; b.h = lo;
  *ph = a.u; *pl = b.u;
}

__global__ __launch_bounds__(256) void wprep_kernel(const float* __restrict__ src,
    unsigned short* __restrict__ dst_hi, unsigned short* __restrict__ dst_lo,
    int K, int N) {
  __shared__ float t[64][65];
  const int k0 = blockIdx.y * 64, n0 = blockIdx.x * 64;
#pragma unroll
  for (int i = 0; i < 16; i++) {
    int idx = threadIdx.x + i * 256;
    int kk = idx >> 6, nn = idx & 63;
    t[kk][nn] = src[(size_t)(k0 + kk) * N + n0 + nn];
  }
  __syncthreads();
#pragma unroll
  for (int i = 0; i < 16; i++) {
    int idx = threadIdx.x + i * 256;
    int nn = idx >> 6, kk = idx & 63;
    unsigned short uh, ul;
    wsplit(t[kk][nn], &uh, &ul);
    dst_hi[(size_t)(n0 + nn) * K + k0 + kk] = uh;
    dst_lo[(size_t)(n0 + nn) * K + k0 + kk] = ul;
  }
}

// 4 DxD matrices in one launch (z = matrix index)
__global__ __launch_bounds__(256) void wprep4_kernel(
    const float* __restrict__ s0, const float* __restrict__ s1,
    const float* __restrict__ s2, const float* __restrict__ s3,
    unsigned short* __restrict__ h0, unsigned short* __restrict__ h1,
    unsigned short* __restrict__ h2, unsigned short* __restrict__ h3,
    unsigned short* __restrict__ l0, unsigned short* __restrict__ l1,
    unsigned short* __restrict__ l2, unsigned short* __restrict__ l3) {
  __shared__ float t[64][65];
  const float* src = blockIdx.z == 0 ? s0 : blockIdx.z == 1 ? s1 : blockIdx.z == 2 ? s2 : s3;
  unsigned short* dh = blockIdx.z == 0 ? h0 : blockIdx.z == 1 ? h1 : blockIdx.z == 2 ? h2 : h3;
  unsigned short* dl = blockIdx.z == 0 ? l0 : blockIdx.z == 1 ? l1 : blockIdx.z == 2 ? l2 : l3;
  const int k0 = blockIdx.y * 64, n0 = blockIdx.x * 64;
#pragma unroll
  for (int i = 0; i < 16; i++) {
    int idx = threadIdx.x + i * 256;
    int kk = idx >> 6, nn = idx & 63;
    t[kk][nn] = src[(size_t)(k0 + kk) * 512 + n0 + nn];
  }
  __syncthreads();
#pragma unroll
  for (int i = 0; i < 16; i++) {
    int idx = threadIdx.x + i * 256;
    int nn = idx >> 6, kk = idx & 63;
    unsigned short uh, ul;
    wsplit(t[kk][nn], &uh, &ul);
    dh[(size_t)(n0 + nn) * 512 + k0 + kk] = uh;
    dl[(size_t)(n0 + nn) * 512 + k0 + kk] = ul;
  }
}

// epi: 1 +bias(null ok)->C, 2 +bias+GELU->C, 3 +bias+posenc->C, 4 C+=acc+bias,
//      5 -> head-separated hi/lo fp16 planes Ph/Pl ([b][h][t][64])
__global__ __launch_bounds__(256) void gemm_split(const float* __restrict__ A,
    const unsigned short* __restrict__ Bhi, const unsigned short* __restrict__ Blo,
    const float* __restrict__ bias, float* __restrict__ C,
    unsigned short* __restrict__ Ph, unsigned short* __restrict__ Pl,
    int M, int N, int K, int ldb, int epi) {
  __shared__ float          As[128 * 64];
  __shared__ unsigned short BsH[128 * 64];
  __shared__ unsigned short BsL[128 * 64];
  const int tid = threadIdx.x;
  const int w = tid >> 6, l = tid & 63;
  const int wm = w >> 1, wn = w & 1;
  const int bm = blockIdx.y * 128, bn = blockIdx.x * 128;
  f32x4 acc[4][4] = {};

  for (int k0 = 0; k0 < K; k0 += 64) {
    if (k0) __syncthreads();
#pragma unroll
    for (int i = 0; i < 8; i++) {
      int cl = i * 256 + w * 64 + l;
      int row = cl >> 4, c = cl & 15;
      int col = (((c >> 1) ^ (row & 7)) * 8) + (c & 1) * 4;
      g2l16(A + (size_t)(bm + row) * K + k0 + col, As + (size_t)(i * 256 + w * 64) * 4);
    }
#pragma unroll
    for (int i = 0; i < 4; i++) {
      int cl = i * 256 + w * 64 + l;
      int row = cl >> 3, c = cl & 7;
      int col = ((c ^ (row & 7)) * 8);
      size_t src = (size_t)(bn + row) * ldb + k0 + col;
      g2l16(Bhi + src, BsH + (size_t)(i * 256 + w * 64) * 8);
      g2l16(Blo + src, BsL + (size_t)(i * 256 + w * 64) * 8);
    }
    __syncthreads();
#pragma unroll
    for (int kk = 0; kk < 2; kk++) {
      f16x8 ahi[4], alo[4], bhi[4], blo[4];
      const int c16 = kk * 4 + (l >> 4);
#pragma unroll
      for (int i = 0; i < 4; i++) {
        int ar = wm * 64 + i * 16 + (l & 15);
        const float* ap = &As[ar * 64 + ((c16 ^ (ar & 7)) * 8)];
        float4 a0 = *(const float4*)ap;
        float4 a1 = *(const float4*)(ap + 4);
        float av[8] = {a0.x, a0.y, a0.z, a0.w, a1.x, a1.y, a1.z, a1.w};
#pragma unroll
        for (int e = 0; e < 8; e++) {
          _Float16 hh = (_Float16)av[e];
          ahi[i][e] = hh;
          alo[i][e] = (_Float16)(av[e] - (float)hh);
        }
        int br = wn * 64 + i * 16 + (l & 15);
        bhi[i] = *(const f16x8*)&BsH[br * 64 + ((c16 ^ (br & 7)) * 8)];
        blo[i] = *(const f16x8*)&BsL[br * 64 + ((c16 ^ (br & 7)) * 8)];
      }
#pragma unroll
      for (int i = 0; i < 4; i++)
#pragma unroll
        for (int j = 0; j < 4; j++) {
          acc[i][j] = __builtin_amdgcn_mfma_f32_16x16x32_f16(ahi[i], bhi[j], acc[i][j], 0, 0, 0);
          acc[i][j] = __builtin_amdgcn_mfma_f32_16x16x32_f16(alo[i], bhi[j], acc[i][j], 0, 0, 0);
          acc[i][j] = __builtin_amdgcn_mfma_f32_16x16x32_f16(ahi[i], blo[j], acc[i][j], 0, 0, 0);
        }
    }
  }

  if (epi == 5) {
#pragma unroll
    for (int i = 0; i < 4; i++)
#pragma unroll
      for (int e = 0; e < 4; e++) {
        int row = bm + wm * 64 + i * 16 + (l >> 4) * 4 + e;
#pragma unroll
        for (int j = 0; j < 4; j++) {
          int col = bn + wn * 64 + j * 16 + (l & 15);
          float vv = acc[i][j][e];
          unsigned short uh, ul;
          wsplit(vv, &uh, &ul);
          size_t off = (size_t)(row >> 10) * 524288 + (size_t)(col >> 6) * 65536
                     + (size_t)(row & 1023) * 64 + (col & 63);
          Ph[off] = uh; Pl[off] = ul;
        }
      }
    return;
  }

  float bj[4], fr[4];
#pragma unroll
  for (int j = 0; j < 4; j++) {
    int col = bn + wn * 64 + j * 16 + (l & 15);
    bj[j] = (bias != nullptr) ? bias[col] : 0.f;
    fr[j] = (epi == 3) ? __expf((float)(col & ~1) * (-9.210340371976184f / 512.0f)) : 0.f;
  }
#pragma unroll
  for (int i = 0; i < 4; i++) {
#pragma unroll
    for (int e = 0; e < 4; e++) {
      int row = bm + wm * 64 + i * 16 + (l >> 4) * 4 + e;
#pragma unroll
      for (int j = 0; j < 4; j++) {
        int col = bn + wn * 64 + j * 16 + (l & 15);
        float v = acc[i][j][e] + bj[j];
        if (epi == 2) v = 0.5f * v * (1.0f + erff(v * 0.70710678118654752f));
        if (epi == 3) {
          float ang = (float)(row & 1023) * fr[j];
          v += (col & 1) ? cosf(ang) : sinf(ang);
        }
        if (epi == 4) v += C[(size_t)row * N + col];
        C[(size_t)row * N + col] = v;
      }
    }
  }
}

__device__ __forceinline__ unsigned f2o(float f) {
  unsigned b = __float_as_uint(f);
  return (b & 0x80000000u) ? ~b : (b | 0x80000000u);
}
__device__ __forceinline__ float o2f(unsigned u) {
  unsigned b = (u & 0x80000000u) ? (u & 0x7fffffffu) : ~u;
  return __uint_as_float(b);
}

// 8 waves, 32 q-rows/block. QK^T via split-fp16 MFMA; S through stride-33 LDS;
// top-k/softmax/PV identical to R8/R9-verified path. 1D grid, XCD-swizzled:
// id%8 == bh%8 -> all 32 t-chunks of one (b,h) share an XCD's L2 (V, K resident).
__global__ __launch_bounds__(512, 4) void attn_kernel(
    const unsigned short* __restrict__ qh, const unsigned short* __restrict__ ql,
    const unsigned short* __restrict__ kh, const unsigned short* __restrict__ kl,
    const float* __restrict__ va, float* __restrict__ ao) {
  __shared__ __align__(16) float smem[14464];
  unsigned short* Qhs = (unsigned short*)smem;    // [32][64] fp16
  unsigned short* Qls = Qhs + 2048;
  unsigned short* Khs = Qhs + 4096;               // [128][64] fp16
  unsigned short* Kls = Qhs + 12288;
  float* S    = smem + 10240;                     // [128][33] fp32
  float* cval = smem + 2048;                      // overlay on Khl: [32][96]
  int*   cidx = (int*)smem + 5120;                // [32][96]

  const int tid = threadIdx.x;
  const int wave = tid >> 6, lane = tid & 63;
  const int id = blockIdx.x;
  const int bh = (id >> 8) * 8 + (id & 7);        // id%8 = bh%8 -> XCD locality
  const int t0 = ((id >> 3) & 31) * 32;
  const int b = bh >> 3, hh = bh & 7;
  const size_t hoff = (size_t)bh * 65536;
  const float* vb = va + (size_t)b * 524288 + hh * 64;

  {  // stage Q (hi/lo), chunk-swizzled source -> linear LDS
    int plane = tid >> 8, cl = tid & 255;
    int row = cl >> 3, c = cl & 7;
    size_t src = hoff + (size_t)(t0 + row) * 64 + ((c ^ (row & 7)) * 8);
    g2l16((plane ? ql : qh) + src, (plane ? Qls : Qhs) + cl * 8);
  }

  float sc[4][16];

  for (int kt = 0; kt < 8; ++kt) {
#pragma unroll
    for (int i = 0; i < 2; ++i) {   // stage K tile (128 rows, hi+lo)
      int cl = tid + i * 512;
      int row = cl >> 3, c = cl & 7;
      size_t src = hoff + (size_t)(kt * 128 + row) * 64 + ((c ^ (row & 7)) * 8);
      g2l16(kh + src, Khs + cl * 8);
      g2l16(kl + src, Kls + cl * 8);
    }
    __syncthreads();

    f32x4 a0 = {}, a1 = {};
#pragma unroll
    for (int ks = 0; ks < 2; ++ks) {
      int c = (lane >> 4) + ks * 4;
      int kr = wave * 16 + (lane & 15);
      int ko = kr * 64 + ((c ^ (kr & 7)) * 8);
      f16x8 kfh = *(const f16x8*)&Khs[ko];
      f16x8 kfl = *(const f16x8*)&Kls[ko];
      int q0 = lane & 15;
      int o0 = q0 * 64 + ((c ^ (q0 & 7)) * 8);
      f16x8 qf0h = *(const f16x8*)&Qhs[o0];
      f16x8 qf0l = *(const f16x8*)&Qls[o0];
      int q1 = 16 + (lane & 15);
      int o1 = q1 * 64 + ((c ^ (q1 & 7)) * 8);
      f16x8 qf1h = *(const f16x8*)&Qhs[o1];
      f16x8 qf1l = *(const f16x8*)&Qls[o1];
      a0 = __builtin_amdgcn_mfma_f32_16x16x32_f16(kfh, qf0h, a0, 0, 0, 0);
      a0 = __builtin_amdgcn_mfma_f32_16x16x32_f16(kfl, qf0h, a0, 0, 0, 0);
      a0 = __builtin_amdgcn_mfma_f32_16x16x32_f16(kfh, qf0l, a0, 0, 0, 0);
      a1 = __builtin_amdgcn_mfma_f32_16x16x32_f16(kfh, qf1h, a1, 0, 0, 0);
      a1 = __builtin_amdgcn_mfma_f32_16x16x32_f16(kfl, qf1h, a1, 0, 0, 0);
      a1 = __builtin_amdgcn_mfma_f32_16x16x32_f16(kfh, qf1l, a1, 0, 0, 0);
    }
#pragma unroll
    for (int e = 0; e < 4; ++e) {
      int srow = wave * 16 + (lane >> 4) * 4 + e;
      S[srow * 33 + (lane & 15)]      = a0[e];
      S[srow * 33 + 16 + (lane & 15)] = a1[e];
    }
    __syncthreads();
#pragma unroll
    for (int r = 0; r < 4; ++r) {
      int qr = wave * 4 + r;
      sc[r][kt * 2]     = S[lane * 33 + qr] * 0.125f;
      sc[r][kt * 2 + 1] = S[(64 + lane) * 33 + qr] * 0.125f;
    }
    __syncthreads();
  }

  unsigned uu[4][16];
#pragma unroll
  for (int r = 0; r < 4; ++r)
#pragma unroll
    for (int j = 0; j < 16; ++j) uu[r][j] = f2o(sc[r][j]);

#pragma unroll
  for (int r = 0; r < 4; ++r) {
    const int row = wave * 4 + r;
    unsigned m = uu[r][0];
#pragma unroll
    for (int j = 1; j < 16; ++j) m = m > uu[r][j] ? m : uu[r][j];
    unsigned gm = m;
#pragma unroll
    for (int off = 32; off; off >>= 1) {
      unsigned o = __shfl_xor(gm, off);
      gm = gm > o ? gm : o;
    }
    unsigned lam = 0;
    for (int bit = 31; bit >= 16; --bit) {
      unsigned tv = lam | (1u << bit);
      if (__popcll(__ballot(m >= tv)) >= 32) lam = tv;
    }
    int base = 0;
#pragma unroll
    for (int j = 0; j < 16; ++j) {
      bool p = uu[r][j] >= lam;
      unsigned long long mk = __ballot(p);
      int pos = base + (int)__popcll(mk & ((1ull << lane) - 1ull));
      if (p && pos < 96) { cval[row * 96 + pos] = o2f(uu[r][j]); cidx[row * 96 + pos] = j * 64 + lane; }
      base += (int)__popcll(mk);
    }
    int C = base;
    unsigned kth = 0;
    if (C <= 96) {
      unsigned cu0 = (lane < C)      ? f2o(cval[row * 96 + lane])      : 0u;
      unsigned cu1 = (64 + lane < C) ? f2o(cval[row * 96 + 64 + lane]) : 0u;
      for (int bit = 31; bit >= 0; --bit) {
        unsigned tv = kth | (1u << bit);
        int c = (int)__popcll(__ballot(cu0 >= tv)) + (int)__popcll(__ballot(cu1 >= tv));
        if (c >= 32) kth = tv;
      }
    } else {
      for (int bit = 31; bit >= 0; --bit) {
        unsigned tv = kth | (1u << bit);
        int pc = 0;
#pragma unroll
        for (int j = 0; j < 16; ++j) pc += (uu[r][j] >= tv) ? 1 : 0;
#pragma unroll
        for (int off = 32; off; off >>= 1) pc += __shfl_xor(pc, off);
        if (pc >= 32) kth = tv;
      }
      base = 0;
#pragma unroll
      for (int j = 0; j < 16; ++j) {
        bool p = uu[r][j] >= kth;
        unsigned long long mk = __ballot(p);
        int pos = base + (int)__popcll(mk & ((1ull << lane) - 1ull));
        if (p && pos < 96) { cval[row * 96 + pos] = o2f(uu[r][j]); cidx[row * 96 + pos] = j * 64 + lane; }
        base += (int)__popcll(mk);
      }
      C = base < 96 ? base : 96;
    }
    float kth_f = o2f(kth), gm_f = o2f(gm);
    float e0 = 0.f, e1 = 0.f;
    if (lane < C)      { float vv = cval[row * 96 + lane];      if (vv >= kth_f) e0 = __expf(vv - gm_f); }
    if (64 + lane < C) { float vv = cval[row * 96 + 64 + lane]; if (vv >= kth_f) e1 = __expf(vv - gm_f); }
    float ps = e0 + e1;
#pragma unroll
    for (int off = 32; off; off >>= 1) ps += __shfl_xor(ps, off);
    cval[row * 96 + lane] = e0;
    if (lane < 32) cval[row * 96 + 64 + lane] = e1;
    float acc = 0.f;
    for (int i = 0; i < C; ++i) {
      float ev = cval[row * 96 + i];
      int   si = cidx[row * 96 + i];
      acc = fmaf(ev, vb[(size_t)si * 512 + lane], acc);
    }
    ao[((size_t)(b * 1024 + t0 + row)) * 512 + hh * 64 + lane] = acc * (1.f / ps);
  }
}

__global__ __launch_bounds__(256) void resid_ln_kernel(float* __restrict__ h,
    const float* __restrict__ o, const float* __restrict__ g,
    const float* __restrict__ be) {
  const int wave = threadIdx.x >> 6, lane = threadIdx.x & 63;
  const size_t row = (size_t)blockIdx.x * 4 + wave;
  float* hr = h + row * 512;
  const float* orr = o + row * 512;
  float x[8]; float s = 0.f, s2 = 0.f;
#pragma unroll
  for (int j = 0; j < 8; j++) {
    float vv = hr[j * 64 + lane] + orr[j * 64 + lane];
    x[j] = vv; s += vv; s2 += vv * vv;
  }
#pragma unroll
  for (int off = 32; off; off >>= 1) { s += __shfl_xor(s, off); s2 += __shfl_xor(s2, off); }
  float mean = s * (1.f / 512.f);
  float var  = s2 * (1.f / 512.f) - mean * mean;
  float r = rsqrtf(var + 1e-5f);
#pragma unroll
  for (int j = 0; j < 8; j++) {
    int d = j * 64 + lane;
    hr[d] = (x[j] - mean) * r * g[d] + be[d];
  }
}

__global__ __launch_bounds__(256) void head_kernel(const float* __restrict__ h,
    const float* __restrict__ gm, const float* __restrict__ bm,
    const float* __restrict__ Wm, const float* __restrict__ cm,
    const float* __restrict__ gs, const float* __restrict__ bs,
    const float* __restrict__ Ws, const float* __restrict__ cs,
    float* __restrict__ out) {
  const int wave = threadIdx.x >> 6, lane = threadIdx.x & 63;
  const int b = blockIdx.x * 4 + wave;
  const float* hr = h + ((size_t)b * 1024 + 1023) * 512;
  float x[8]; float s = 0.f, s2 = 0.f;
#pragma unroll
  for (int j = 0; j < 8; j++) { float vv = hr[j * 64 + lane]; x[j] = vv; s += vv; s2 += vv * vv; }
#pragma unroll
  for (int off = 32; off; off >>= 1) { s += __shfl_xor(s, off); s2 += __shfl_xor(s2, off); }
  float mean = s * (1.f / 512.f);
  float var  = s2 * (1.f / 512.f) - mean * mean;
  float r = rsqrtf(var + 1e-5f);
  float am = 0.f, as = 0.f;
#pragma unroll
  for (int j = 0; j < 8; j++) {
    int d = j * 64 + lane;
    float n = (x[j] - mean) * r;
    am = fmaf(n * gm[d] + bm[d], Wm[d], am);
    as = fmaf(n * gs[d] + bs[d], Ws[d], as);
  }
#pragma unroll
  for (int off = 32; off; off >>= 1) { am += __shfl_xor(am, off); as += __shfl_xor(as, off); }
  if (lane == 0) {
    const double Z = 2.326347874040841;
    float mu  = am + cm[0];
    float scl = 1.f / (1.f + expf(-(as + cs[0])));
    float esc = (float)(exp(-0.5 * Z * Z) / sqrt(2.0 * 3.14159265358979323846) / 0.01);
    out[b]      = mu;
    out[16 + b] = scl;
    out[32 + b] = mu + scl * (float)Z;
    out[48 + b] = mu + scl * esc;
  }
}

extern "C" void kernel_launch(void* const* d_in, const int* in_sizes, int n_in,
                              void* d_out, int out_size, void* d_ws, size_t ws_size,
                              hipStream_t stream) {
  const float* x    = (const float*)d_in[0];
  const float* W_in = (const float*)d_in[1];
  const float* b_in = (const float*)d_in[2];
  const float* Wq   = (const float*)d_in[3];
  const float* Wk   = (const float*)d_in[4];
  const float* Wv   = (const float*)d_in[5];
  const float* Wo   = (const float*)d_in[6];
  const float* bo   = (const float*)d_in[7];
  const float* W1   = (const float*)d_in[8];
  const float* b1   = (const float*)d_in[9];
  const float* W2   = (const float*)d_in[10];
  const float* b2   = (const float*)d_in[11];
  const float* g1   = (const float*)d_in[12];
  const float* be1  = (const float*)d_in[13];
  const float* g2   = (const float*)d_in[14];
  const float* be2  = (const float*)d_in[15];
  const float* gm   = (const float*)d_in[16];
  const float* bm   = (const float*)d_in[17];
  const float* Wm   = (const float*)d_in[18];
  const float* cm   = (const float*)d_in[19];
  const float* gs   = (const float*)d_in[20];
  const float* bs   = (const float*)d_in[21];
  const float* Ws   = (const float*)d_in[22];
  const float* cs   = (const float*)d_in[23];

  const int M = 16384, D = 512, DFF = 2048;
  float* ws = (float*)d_ws;
  float* h   = ws;                                   // [16384][512] fp32
  unsigned short* qhp = (unsigned short*)(ws + 8388608);   // [128][1024][64] hi
  unsigned short* qlp = qhp + 8388608;                     // lo
  unsigned short* khp = (unsigned short*)(ws + 16777216);
  unsigned short* klp = khp + 8388608;
  float* v   = ws + 25165824;                        // V fp32 / Wo-out
  float* ao  = ws + 33554432;                        // attn-out / FFN2-out
  float* ff  = ws + 8388608;                         // FFN half [16384][1024]
  unsigned short* wl = (unsigned short*)(ws + 41943040);   // per-layer planes
  unsigned short* WqH = wl,            *WqL = wl + 262144;
  unsigned short* WkH = wl + 524288,   *WkL = wl + 786432;
  unsigned short* WvH = wl + 1048576,  *WvL = wl + 1310720;
  unsigned short* WoH = wl + 1572864,  *WoL = wl + 1835008;
  unsigned short* W1H = wl + 2097152,  *W1L = wl + 3145728;
  unsigned short* W2H = wl + 4194304,  *W2L = wl + 5242880;
  unsigned short* WinH = (unsigned short*)(ws + 45088768);
  unsigned short* WinL = WinH + 32768;

  dim3 blk(256);
  dim3 gD(4, 128);    // N=512
  dim3 gH(8, 128);    // N=1024 (FFN1 half)

  wprep_kernel<<<dim3(8, 1, 1), blk, 0, stream>>>(W_in, WinH, WinL, 64, 512);
  gemm_split<<<gD, blk, 0, stream>>>(x, WinH, WinL, b_in, h, nullptr, nullptr, M, D, 64, 64, 3);

  for (int l = 0; l < 4; l++) {
    const float* wq = Wq + (size_t)l * 262144;
    const float* wk = Wk + (size_t)l * 262144;
    const float* wv = Wv + (size_t)l * 262144;
    const float* wo = Wo + (size_t)l * 262144;
    const float* w1 = W1 + (size_t)l * 1048576;
    const float* w2 = W2 + (size_t)l * 1048576;

    wprep4_kernel<<<dim3(8, 8, 4), blk, 0, stream>>>(wq, wk, wv, wo,
        WqH, WkH, WvH, WoH, WqL, WkL, WvL, WoL);
    wprep_kernel<<<dim3(32, 8, 1), blk, 0, stream>>>(w1, W1H, W1L, 512, 2048);
    wprep_kernel<<<dim3(8, 32, 1), blk, 0, stream>>>(w2, W2H, W2L, 2048, 512);

    gemm_split<<<gD, blk, 0, stream>>>(h, WqH, WqL, nullptr, nullptr, qhp, qlp, M, D, D, D, 5);
    gemm_split<<<gD, blk, 0, stream>>>(h, WkH, WkL, nullptr, nullptr, khp, klp, M, D, D, D, 5);
    gemm_split<<<gD, blk, 0, stream>>>(h, WvH, WvL, nullptr, v, nullptr, nullptr, M, D, D, D, 1);

    attn_kernel<<<dim3(4096), dim3(512), 0, stream>>>(qhp, qlp, khp, klp, v, ao);

    gemm_split<<<gD, blk, 0, stream>>>(ao, WoH, WoL, bo + (size_t)l * D, v, nullptr, nullptr, M, D, D, D, 1);
    resid_ln_kernel<<<dim3(4096), blk, 0, stream>>>(h, v, g1 + (size_t)l * D, be1 + (size_t)l * D);

    gemm_split<<<gH, blk, 0, stream>>>(h, W1H, W1L, b1 + (size_t)l * DFF, ff, nullptr, nullptr, M, 1024, D, D, 2);
    gemm_split<<<gD, blk, 0, stream>>>(ff, W2H, W2L, nullptr, ao, nullptr, nullptr, M, D, 1024, DFF, 1);
    gemm_split<<<gH, blk, 0, stream>>>(h, W1H + 524288, W1L + 524288,
                                       b1 + (size_t)l * DFF + 1024, ff, nullptr, nullptr, M, 1024, D, D, 2);
    gemm_split<<<gD, blk, 0, stream>>>(ff, W2H + 1024, W2L + 1024,
                                       b2 + (size_t)l * D, ao, nullptr, nullptr, M, D, 1024, DFF, 4);

    resid_ln_kernel<<<dim3(4096), blk, 0, stream>>>(h, ao, g2 + (size_t)l * D, be2 + (size_t)l * D);
  }

  head_kernel<<<dim3(4), blk, 0, stream>>>(h, gm, bm, Wm, cm, gs, bs, Ws, cs, (float*)d_out);
}

// Round 11
// 3091.832 us; speedup vs baseline: 8.7868x; 1.0339x over previous
//
#include <hip/hip_runtime.h>
#include <math.h>

// fp32 activations; weights + Q/K split to hi/lo fp16 planes (w=hi+lo).
// GEMM + attn QK^T = 3 MFMAs/fragment (hi*hi + lo*hi + hi*lo), fp32 accum.
// B=16,T=1024,Din=64,D=512,Dff=2048,L=4,H=8,dh=64,TOPK=32,M=16384.
// R11: PV gather batched 8-deep (float4/int4 LDS reads, 8 V-loads in flight)
// -- R10 showed PV is L2-latency-bound, not BW-bound (FETCH 273->49MB, dur -8%).

typedef unsigned int u32;
typedef __attribute__((ext_vector_type(8))) _Float16 f16x8;
typedef __attribute__((ext_vector_type(4))) float f32x4;

__device__ __forceinline__ void g2l16(const void* g, void* l) {
  __builtin_amdgcn_global_load_lds(
      (const __attribute__((address_space(1))) u32*)g,
      (__attribute__((address_space(3))) u32*)l, 16, 0, 0);
}

__device__ __forceinline__ void wsplit(float w, unsigned short* ph, unsigned short* pl) {
  _Float16 hi = (_Float16)w;
  _Float16 lo = (_Float16)(w - (float)hi);
  union { _Float16 h; unsigned short u; } a, b; a.h = hi; b.h = lo;
  *ph = a.u; *pl = b.u;
}

__global__ __launch_bounds__(256) void wprep_kernel(const float* __restrict__ src,
    unsigned short* __restrict__ dst_hi, unsigned short* __restrict__ dst_lo,
    int K, int N) {
  __shared__ float t[64][65];
  const int k0 = blockIdx.y * 64, n0 = blockIdx.x * 64;
#pragma unroll
  for (int i = 0; i < 16; i++) {
    int idx = threadIdx.x + i * 256;
    int kk = idx >> 6, nn = idx & 63;
    t[kk][nn] = src[(size_t)(k0 + kk) * N + n0 + nn];
  }
  __syncthreads();
#pragma unroll
  for (int i = 0; i < 16; i++) {
    int idx = threadIdx.x + i * 256;
    int nn = idx >> 6, kk = idx & 63;
    unsigned short uh, ul;
    wsplit(t[kk][nn], &uh, &ul);
    dst_hi[(size_t)(n0 + nn) * K + k0 + kk] = uh;
    dst_lo[(size_t)(n0 + nn) * K + k0 + kk] = ul;
  }
}

// 4 DxD matrices in one launch (z = matrix index)
__global__ __launch_bounds__(256) void wprep4_kernel(
    const float* __restrict__ s0, const float* __restrict__ s1,
    const float* __restrict__ s2, const float* __restrict__ s3,
    unsigned short* __restrict__ h0, unsigned short* __restrict__ h1,
    unsigned short* __restrict__ h2, unsigned short* __restrict__ h3,
    unsigned short* __restrict__ l0, unsigned short* __restrict__ l1,
    unsigned short* __restrict__ l2, unsigned short* __restrict__ l3) {
  __shared__ float t[64][65];
  const float* src = blockIdx.z == 0 ? s0 : blockIdx.z == 1 ? s1 : blockIdx.z == 2 ? s2 : s3;
  unsigned short* dh = blockIdx.z == 0 ? h0 : blockIdx.z == 1 ? h1 : blockIdx.z == 2 ? h2 : h3;
  unsigned short* dl = blockIdx.z == 0 ? l0 : blockIdx.z == 1 ? l1 : blockIdx.z == 2 ? l2 : l3;
  const int k0 = blockIdx.y * 64, n0 = blockIdx.x * 64;
#pragma unroll
  for (int i = 0; i < 16; i++) {
    int idx = threadIdx.x + i * 256;
    int kk = idx >> 6, nn = idx & 63;
    t[kk][nn] = src[(size_t)(k0 + kk) * 512 + n0 + nn];
  }
  __syncthreads();
#pragma unroll
  for (int i = 0; i < 16; i++) {
    int idx = threadIdx.x + i * 256;
    int nn = idx >> 6, kk = idx & 63;
    unsigned short uh, ul;
    wsplit(t[kk][nn], &uh, &ul);
    dh[(size_t)(n0 + nn) * 512 + k0 + kk] = uh;
    dl[(size_t)(n0 + nn) * 512 + k0 + kk] = ul;
  }
}

// epi: 1 +bias(null ok)->C, 2 +bias+GELU->C, 3 +bias+posenc->C, 4 C+=acc+bias,
//      5 -> head-separated hi/lo fp16 planes Ph/Pl ([b][h][t][64])
__global__ __launch_bounds__(256) void gemm_split(const float* __restrict__ A,
    const unsigned short* __restrict__ Bhi, const unsigned short* __restrict__ Blo,
    const float* __restrict__ bias, float* __restrict__ C,
    unsigned short* __restrict__ Ph, unsigned short* __restrict__ Pl,
    int M, int N, int K, int ldb, int epi) {
  __shared__ float          As[128 * 64];
  __shared__ unsigned short BsH[128 * 64];
  __shared__ unsigned short BsL[128 * 64];
  const int tid = threadIdx.x;
  const int w = tid >> 6, l = tid & 63;
  const int wm = w >> 1, wn = w & 1;
  const int bm = blockIdx.y * 128, bn = blockIdx.x * 128;
  f32x4 acc[4][4] = {};

  for (int k0 = 0; k0 < K; k0 += 64) {
    if (k0) __syncthreads();
#pragma unroll
    for (int i = 0; i < 8; i++) {
      int cl = i * 256 + w * 64 + l;
      int row = cl >> 4, c = cl & 15;
      int col = (((c >> 1) ^ (row & 7)) * 8) + (c & 1) * 4;
      g2l16(A + (size_t)(bm + row) * K + k0 + col, As + (size_t)(i * 256 + w * 64) * 4);
    }
#pragma unroll
    for (int i = 0; i < 4; i++) {
      int cl = i * 256 + w * 64 + l;
      int row = cl >> 3, c = cl & 7;
      int col = ((c ^ (row & 7)) * 8);
      size_t src = (size_t)(bn + row) * ldb + k0 + col;
      g2l16(Bhi + src, BsH + (size_t)(i * 256 + w * 64) * 8);
      g2l16(Blo + src, BsL + (size_t)(i * 256 + w * 64) * 8);
    }
    __syncthreads();
#pragma unroll
    for (int kk = 0; kk < 2; kk++) {
      f16x8 ahi[4], alo[4], bhi[4], blo[4];
      const int c16 = kk * 4 + (l >> 4);
#pragma unroll
      for (int i = 0; i < 4; i++) {
        int ar = wm * 64 + i * 16 + (l & 15);
        const float* ap = &As[ar * 64 + ((c16 ^ (ar & 7)) * 8)];
        float4 a0 = *(const float4*)ap;
        float4 a1 = *(const float4*)(ap + 4);
        float av[8] = {a0.x, a0.y, a0.z, a0.w, a1.x, a1.y, a1.z, a1.w};
#pragma unroll
        for (int e = 0; e < 8; e++) {
          _Float16 hh = (_Float16)av[e];
          ahi[i][e] = hh;
          alo[i][e] = (_Float16)(av[e] - (float)hh);
        }
        int br = wn * 64 + i * 16 + (l & 15);
        bhi[i] = *(const f16x8*)&BsH[br * 64 + ((c16 ^ (br & 7)) * 8)];
        blo[i] = *(const f16x8*)&BsL[br * 64 + ((c16 ^ (br & 7)) * 8)];
      }
#pragma unroll
      for (int i = 0; i < 4; i++)
#pragma unroll
        for (int j = 0; j < 4; j++) {
          acc[i][j] = __builtin_amdgcn_mfma_f32_16x16x32_f16(ahi[i], bhi[j], acc[i][j], 0, 0, 0);
          acc[i][j] = __builtin_amdgcn_mfma_f32_16x16x32_f16(alo[i], bhi[j], acc[i][j], 0, 0, 0);
          acc[i][j] = __builtin_amdgcn_mfma_f32_16x16x32_f16(ahi[i], blo[j], acc[i][j], 0, 0, 0);
        }
    }
  }

  if (epi == 5) {
#pragma unroll
    for (int i = 0; i < 4; i++)
#pragma unroll
      for (int e = 0; e < 4; e++) {
        int row = bm + wm * 64 + i * 16 + (l >> 4) * 4 + e;
#pragma unroll
        for (int j = 0; j < 4; j++) {
          int col = bn + wn * 64 + j * 16 + (l & 15);
          float vv = acc[i][j][e];
          unsigned short uh, ul;
          wsplit(vv, &uh, &ul);
          size_t off = (size_t)(row >> 10) * 524288 + (size_t)(col >> 6) * 65536
                     + (size_t)(row & 1023) * 64 + (col & 63);
          Ph[off] = uh; Pl[off] = ul;
        }
      }
    return;
  }

  float bj[4], fr[4];
#pragma unroll
  for (int j = 0; j < 4; j++) {
    int col = bn + wn * 64 + j * 16 + (l & 15);
    bj[j] = (bias != nullptr) ? bias[col] : 0.f;
    fr[j] = (epi == 3) ? __expf((float)(col & ~1) * (-9.210340371976184f / 512.0f)) : 0.f;
  }
#pragma unroll
  for (int i = 0; i < 4; i++) {
#pragma unroll
    for (int e = 0; e < 4; e++) {
      int row = bm + wm * 64 + i * 16 + (l >> 4) * 4 + e;
#pragma unroll
      for (int j = 0; j < 4; j++) {
        int col = bn + wn * 64 + j * 16 + (l & 15);
        float v = acc[i][j][e] + bj[j];
        if (epi == 2) v = 0.5f * v * (1.0f + erff(v * 0.70710678118654752f));
        if (epi == 3) {
          float ang = (float)(row & 1023) * fr[j];
          v += (col & 1) ? cosf(ang) : sinf(ang);
        }
        if (epi == 4) v += C[(size_t)row * N + col];
        C[(size_t)row * N + col] = v;
      }
    }
  }
}

__device__ __forceinline__ unsigned f2o(float f) {
  unsigned b = __float_as_uint(f);
  return (b & 0x80000000u) ? ~b : (b | 0x80000000u);
}
__device__ __forceinline__ float o2f(unsigned u) {
  unsigned b = (u & 0x80000000u) ? (u & 0x7fffffffu) : ~u;
  return __uint_as_float(b);
}

// 8 waves, 32 q-rows/block. QK^T via split-fp16 MFMA; S through stride-33 LDS;
// top-k identical to R8-R10 verified path; PV gather batched 8-deep.
// 1D grid, XCD-swizzled: id%8 == bh%8.
__global__ __launch_bounds__(512, 4) void attn_kernel(
    const unsigned short* __restrict__ qh, const unsigned short* __restrict__ ql,
    const unsigned short* __restrict__ kh, const unsigned short* __restrict__ kl,
    const float* __restrict__ va, float* __restrict__ ao) {
  __shared__ __align__(16) float smem[14464];
  unsigned short* Qhs = (unsigned short*)smem;    // [32][64] fp16
  unsigned short* Qls = Qhs + 2048;
  unsigned short* Khs = Qhs + 4096;               // [128][64] fp16
  unsigned short* Kls = Qhs + 12288;
  float* S    = smem + 10240;                     // [128][33] fp32
  float* cval = smem + 2048;                      // overlay on K: [32][104]
  int*   cidx = (int*)smem + 5376;                // [32][104]

  const int tid = threadIdx.x;
  const int wave = tid >> 6, lane = tid & 63;
  const int id = blockIdx.x;
  const int bh = (id >> 8) * 8 + (id & 7);        // id%8 = bh%8 -> XCD locality
  const int t0 = ((id >> 3) & 31) * 32;
  const int b = bh >> 3, hh = bh & 7;
  const size_t hoff = (size_t)bh * 65536;
  const float* vb = va + (size_t)b * 524288 + hh * 64;

  {  // stage Q (hi/lo), chunk-swizzled source -> linear LDS
    int plane = tid >> 8, cl = tid & 255;
    int row = cl >> 3, c = cl & 7;
    size_t src = hoff + (size_t)(t0 + row) * 64 + ((c ^ (row & 7)) * 8);
    g2l16((plane ? ql : qh) + src, (plane ? Qls : Qhs) + cl * 8);
  }

  float sc[4][16];

  for (int kt = 0; kt < 8; ++kt) {
#pragma unroll
    for (int i = 0; i < 2; ++i) {   // stage K tile (128 rows, hi+lo)
      int cl = tid + i * 512;
      int row = cl >> 3, c = cl & 7;
      size_t src = hoff + (size_t)(kt * 128 + row) * 64 + ((c ^ (row & 7)) * 8);
      g2l16(kh + src, Khs + cl * 8);
      g2l16(kl + src, Kls + cl * 8);
    }
    __syncthreads();

    f32x4 a0 = {}, a1 = {};
#pragma unroll
    for (int ks = 0; ks < 2; ++ks) {
      int c = (lane >> 4) + ks * 4;
      int kr = wave * 16 + (lane & 15);
      int ko = kr * 64 + ((c ^ (kr & 7)) * 8);
      f16x8 kfh = *(const f16x8*)&Khs[ko];
      f16x8 kfl = *(const f16x8*)&Kls[ko];
      int q0 = lane & 15;
      int o0 = q0 * 64 + ((c ^ (q0 & 7)) * 8);
      f16x8 qf0h = *(const f16x8*)&Qhs[o0];
      f16x8 qf0l = *(const f16x8*)&Qls[o0];
      int q1 = 16 + (lane & 15);
      int o1 = q1 * 64 + ((c ^ (q1 & 7)) * 8);
      f16x8 qf1h = *(const f16x8*)&Qhs[o1];
      f16x8 qf1l = *(const f16x8*)&Qls[o1];
      a0 = __builtin_amdgcn_mfma_f32_16x16x32_f16(kfh, qf0h, a0, 0, 0, 0);
      a0 = __builtin_amdgcn_mfma_f32_16x16x32_f16(kfl, qf0h, a0, 0, 0, 0);
      a0 = __builtin_amdgcn_mfma_f32_16x16x32_f16(kfh, qf0l, a0, 0, 0, 0);
      a1 = __builtin_amdgcn_mfma_f32_16x16x32_f16(kfh, qf1h, a1, 0, 0, 0);
      a1 = __builtin_amdgcn_mfma_f32_16x16x32_f16(kfl, qf1h, a1, 0, 0, 0);
      a1 = __builtin_amdgcn_mfma_f32_16x16x32_f16(kfh, qf1l, a1, 0, 0, 0);
    }
#pragma unroll
    for (int e = 0; e < 4; ++e) {
      int srow = wave * 16 + (lane >> 4) * 4 + e;
      S[srow * 33 + (lane & 15)]      = a0[e];
      S[srow * 33 + 16 + (lane & 15)] = a1[e];
    }
    __syncthreads();
#pragma unroll
    for (int r = 0; r < 4; ++r) {
      int qr = wave * 4 + r;
      sc[r][kt * 2]     = S[lane * 33 + qr] * 0.125f;
      sc[r][kt * 2 + 1] = S[(64 + lane) * 33 + qr] * 0.125f;
    }
    __syncthreads();
  }

  unsigned uu[4][16];
#pragma unroll
  for (int r = 0; r < 4; ++r)
#pragma unroll
    for (int j = 0; j < 16; ++j) uu[r][j] = f2o(sc[r][j]);

#pragma unroll
  for (int r = 0; r < 4; ++r) {
    const int row = wave * 4 + r;
    unsigned m = uu[r][0];
#pragma unroll
    for (int j = 1; j < 16; ++j) m = m > uu[r][j] ? m : uu[r][j];
    unsigned gm = m;
#pragma unroll
    for (int off = 32; off; off >>= 1) {
      unsigned o = __shfl_xor(gm, off);
      gm = gm > o ? gm : o;
    }
    unsigned lam = 0;
    for (int bit = 31; bit >= 16; --bit) {
      unsigned tv = lam | (1u << bit);
      if (__popcll(__ballot(m >= tv)) >= 32) lam = tv;
    }
    int base = 0;
#pragma unroll
    for (int j = 0; j < 16; ++j) {
      bool p = uu[r][j] >= lam;
      unsigned long long mk = __ballot(p);
      int pos = base + (int)__popcll(mk & ((1ull << lane) - 1ull));
      if (p && pos < 96) { cval[row * 104 + pos] = o2f(uu[r][j]); cidx[row * 104 + pos] = j * 64 + lane; }
      base += (int)__popcll(mk);
    }
    int C = base;
    unsigned kth = 0;
    if (C <= 96) {
      unsigned cu0 = (lane < C)      ? f2o(cval[row * 104 + lane])      : 0u;
      unsigned cu1 = (64 + lane < C) ? f2o(cval[row * 104 + 64 + lane]) : 0u;
      for (int bit = 31; bit >= 0; --bit) {
        unsigned tv = kth | (1u << bit);
        int c = (int)__popcll(__ballot(cu0 >= tv)) + (int)__popcll(__ballot(cu1 >= tv));
        if (c >= 32) kth = tv;
      }
    } else {
      for (int bit = 31; bit >= 0; --bit) {
        unsigned tv = kth | (1u << bit);
        int pc = 0;
#pragma unroll
        for (int j = 0; j < 16; ++j) pc += (uu[r][j] >= tv) ? 1 : 0;
#pragma unroll
        for (int off = 32; off; off >>= 1) pc += __shfl_xor(pc, off);
        if (pc >= 32) kth = tv;
      }
      base = 0;
#pragma unroll
      for (int j = 0; j < 16; ++j) {
        bool p = uu[r][j] >= kth;
        unsigned long long mk = __ballot(p);
        int pos = base + (int)__popcll(mk & ((1ull << lane) - 1ull));
        if (p && pos < 96) { cval[row * 104 + pos] = o2f(uu[r][j]); cidx[row * 104 + pos] = j * 64 + lane; }
        base += (int)__popcll(mk);
      }
      C = base < 96 ? base : 96;
    }
    float kth_f = o2f(kth), gm_f = o2f(gm);
    float e0 = 0.f, e1 = 0.f;
    if (lane < C)      { float vv = cval[row * 104 + lane];      if (vv >= kth_f) e0 = __expf(vv - gm_f); }
    if (64 + lane < C) { float vv = cval[row * 104 + 64 + lane]; if (vv >= kth_f) e1 = __expf(vv - gm_f); }
    float ps = e0 + e1;
#pragma unroll
    for (int off = 32; off; off >>= 1) ps += __shfl_xor(ps, off);
    // writeback: entries [0,64) = e0 (0 beyond C), [64,96) = e1, [96,104) = 0
    cval[row * 104 + lane] = e0;
    if (lane < 32) cval[row * 104 + 64 + lane] = e1;
    if (lane < 8)  cval[row * 104 + 96 + lane] = 0.f;
    // cidx pad: entries [C,104) -> 0 (ev=0 there; masked anyway)
    { int p = C + lane;      if (p < 104) cidx[row * 104 + p] = 0; }
    { int p = C + 64 + lane; if (p < 104) cidx[row * 104 + p] = 0; }

    // PV, batched 8-deep: 8 independent V-row loads in flight per step
    float acc = 0.f;
    int C8 = (C + 7) & ~7;
    for (int i0 = 0; i0 < C8; i0 += 8) {
      float4 ev0 = *(const float4*)&cval[row * 104 + i0];
      float4 ev1 = *(const float4*)&cval[row * 104 + i0 + 4];
      int4  si0 = *(const int4*)&cidx[row * 104 + i0];
      int4  si1 = *(const int4*)&cidx[row * 104 + i0 + 4];
      float v0 = vb[(size_t)(si0.x & 1023) * 512 + lane];
      float v1 = vb[(size_t)(si0.y & 1023) * 512 + lane];
      float v2 = vb[(size_t)(si0.z & 1023) * 512 + lane];
      float v3 = vb[(size_t)(si0.w & 1023) * 512 + lane];
      float v4 = vb[(size_t)(si1.x & 1023) * 512 + lane];
      float v5 = vb[(size_t)(si1.y & 1023) * 512 + lane];
      float v6 = vb[(size_t)(si1.z & 1023) * 512 + lane];
      float v7 = vb[(size_t)(si1.w & 1023) * 512 + lane];
      acc = fmaf(ev0.x, v0, acc); acc = fmaf(ev0.y, v1, acc);
      acc = fmaf(ev0.z, v2, acc); acc = fmaf(ev0.w, v3, acc);
      acc = fmaf(ev1.x, v4, acc); acc = fmaf(ev1.y, v5, acc);
      acc = fmaf(ev1.z, v6, acc); acc = fmaf(ev1.w, v7, acc);
    }
    ao[((size_t)(b * 1024 + t0 + row)) * 512 + hh * 64 + lane] = acc * (1.f / ps);
  }
}

__global__ __launch_bounds__(256) void resid_ln_kernel(float* __restrict__ h,
    const float* __restrict__ o, const float* __restrict__ g,
    const float* __restrict__ be) {
  const int wave = threadIdx.x >> 6, lane = threadIdx.x & 63;
  const size_t row = (size_t)blockIdx.x * 4 + wave;
  float* hr = h + row * 512;
  const float* orr = o + row * 512;
  float x[8]; float s = 0.f, s2 = 0.f;
#pragma unroll
  for (int j = 0; j < 8; j++) {
    float vv = hr[j * 64 + lane] + orr[j * 64 + lane];
    x[j] = vv; s += vv; s2 += vv * vv;
  }
#pragma unroll
  for (int off = 32; off; off >>= 1) { s += __shfl_xor(s, off); s2 += __shfl_xor(s2, off); }
  float mean = s * (1.f / 512.f);
  float var  = s2 * (1.f / 512.f) - mean * mean;
  float r = rsqrtf(var + 1e-5f);
#pragma unroll
  for (int j = 0; j < 8; j++) {
    int d = j * 64 + lane;
    hr[d] = (x[j] - mean) * r * g[d] + be[d];
  }
}

__global__ __launch_bounds__(256) void head_kernel(const float* __restrict__ h,
    const float* __restrict__ gm, const float* __restrict__ bm,
    const float* __restrict__ Wm, const float* __restrict__ cm,
    const float* __restrict__ gs, const float* __restrict__ bs,
    const float* __restrict__ Ws, const float* __restrict__ cs,
    float* __restrict__ out) {
  const int wave = threadIdx.x >> 6, lane = threadIdx.x & 63;
  const int b = blockIdx.x * 4 + wave;
  const float* hr = h + ((size_t)b * 1024 + 1023) * 512;
  float x[8]; float s = 0.f, s2 = 0.f;
#pragma unroll
  for (int j = 0; j < 8; j++) { float vv = hr[j * 64 + lane]; x[j] = vv; s += vv; s2 += vv * vv; }
#pragma unroll
  for (int off = 32; off; off >>= 1) { s += __shfl_xor(s, off); s2 += __shfl_xor(s2, off); }
  float mean = s * (1.f / 512.f);
  float var  = s2 * (1.f / 512.f) - mean * mean;
  float r = rsqrtf(var + 1e-5f);
  float am = 0.f, as = 0.f;
#pragma unroll
  for (int j = 0; j < 8; j++) {
    int d = j * 64 + lane;
    float n = (x[j] - mean) * r;
    am = fmaf(n * gm[d] + bm[d], Wm[d], am);
    as = fmaf(n * gs[d] + bs[d], Ws[d], as);
  }
#pragma unroll
  for (int off = 32; off; off >>= 1) { am += __shfl_xor(am, off); as += __shfl_xor(as, off); }
  if (lane == 0) {
    const double Z = 2.326347874040841;
    float mu  = am + cm[0];
    float scl = 1.f / (1.f + expf(-(as + cs[0])));
    float esc = (float)(exp(-0.5 * Z * Z) / sqrt(2.0 * 3.14159265358979323846) / 0.01);
    out[b]      = mu;
    out[16 + b] = scl;
    out[32 + b] = mu + scl * (float)Z;
    out[48 + b] = mu + scl * esc;
  }
}

extern "C" void kernel_launch(void* const* d_in, const int* in_sizes, int n_in,
                              void* d_out, int out_size, void* d_ws, size_t ws_size,
                              hipStream_t stream) {
  const float* x    = (const float*)d_in[0];
  const float* W_in = (const float*)d_in[1];
  const float* b_in = (const float*)d_in[2];
  const float* Wq   = (const float*)d_in[3];
  const float* Wk   = (const float*)d_in[4];
  const float* Wv   = (const float*)d_in[5];
  const float* Wo   = (const float*)d_in[6];
  const float* bo   = (const float*)d_in[7];
  const float* W1   = (const float*)d_in[8];
  const float* b1   = (const float*)d_in[9];
  const float* W2   = (const float*)d_in[10];
  const float* b2   = (const float*)d_in[11];
  const float* g1   = (const float*)d_in[12];
  const float* be1  = (const float*)d_in[13];
  const float* g2   = (const float*)d_in[14];
  const float* be2  = (const float*)d_in[15];
  const float* gm   = (const float*)d_in[16];
  const float* bm   = (const float*)d_in[17];
  const float* Wm   = (const float*)d_in[18];
  const float* cm   = (const float*)d_in[19];
  const float* gs   = (const float*)d_in[20];
  const float* bs   = (const float*)d_in[21];
  const float* Ws   = (const float*)d_in[22];
  const float* cs   = (const float*)d_in[23];

  const int M = 16384, D = 512, DFF = 2048;
  float* ws = (float*)d_ws;
  float* h   = ws;                                   // [16384][512] fp32
  unsigned short* qhp = (unsigned short*)(ws + 8388608);   // [128][1024][64] hi
  unsigned short* qlp = qhp + 8388608;                     // lo
  unsigned short* khp = (unsigned short*)(ws + 16777216);
  unsigned short* klp = khp + 8388608;
  float* v   = ws + 25165824;                        // V fp32 / Wo-out
  float* ao  = ws + 33554432;                        // attn-out / FFN2-out
  float* ff  = ws + 8388608;                         // FFN half [16384][1024]
  unsigned short* wl = (unsigned short*)(ws + 41943040);   // per-layer planes
  unsigned short* WqH = wl,            *WqL = wl + 262144;
  unsigned short* WkH = wl + 524288,   *WkL = wl + 786432;
  unsigned short* WvH = wl + 1048576,  *WvL = wl + 1310720;
  unsigned short* WoH = wl + 1572864,  *WoL = wl + 1835008;
  unsigned short* W1H = wl + 2097152,  *W1L = wl + 3145728;
  unsigned short* W2H = wl + 4194304,  *W2L = wl + 5242880;
  unsigned short* WinH = (unsigned short*)(ws + 45088768);
  unsigned short* WinL = WinH + 32768;

  dim3 blk(256);
  dim3 gD(4, 128);    // N=512
  dim3 gH(8, 128);    // N=1024 (FFN1 half)

  wprep_kernel<<<dim3(8, 1, 1), blk, 0, stream>>>(W_in, WinH, WinL, 64, 512);
  gemm_split<<<gD, blk, 0, stream>>>(x, WinH, WinL, b_in, h, nullptr, nullptr, M, D, 64, 64, 3);

  for (int l = 0; l < 4; l++) {
    const float* wq = Wq + (size_t)l * 262144;
    const float* wk = Wk + (size_t)l * 262144;
    const float* wv = Wv + (size_t)l * 262144;
    const float* wo = Wo + (size_t)l * 262144;
    const float* w1 = W1 + (size_t)l * 1048576;
    const float* w2 = W2 + (size_t)l * 1048576;

    wprep4_kernel<<<dim3(8, 8, 4), blk, 0, stream>>>(wq, wk, wv, wo,
        WqH, WkH, WvH, WoH, WqL, WkL, WvL, WoL);
    wprep_kernel<<<dim3(32, 8, 1), blk, 0, stream>>>(w1, W1H, W1L, 512, 2048);
    wprep_kernel<<<dim3(8, 32, 1), blk, 0, stream>>>(w2, W2H, W2L, 2048, 512);

    gemm_split<<<gD, blk, 0, stream>>>(h, WqH, WqL, nullptr, nullptr, qhp, qlp, M, D, D, D, 5);
    gemm_split<<<gD, blk, 0, stream>>>(h, WkH, WkL, nullptr, nullptr, khp, klp, M, D, D, D, 5);
    gemm_split<<<gD, blk, 0, stream>>>(h, WvH, WvL, nullptr, v, nullptr, nullptr, M, D, D, D, 1);

    attn_kernel<<<dim3(4096), dim3(512), 0, stream>>>(qhp, qlp, khp, klp, v, ao);

    gemm_split<<<gD, blk, 0, stream>>>(ao, WoH, WoL, bo + (size_t)l * D, v, nullptr, nullptr, M, D, D, D, 1);
    resid_ln_kernel<<<dim3(4096), blk, 0, stream>>>(h, v, g1 + (size_t)l * D, be1 + (size_t)l * D);

    gemm_split<<<gH, blk, 0, stream>>>(h, W1H, W1L, b1 + (size_t)l * DFF, ff, nullptr, nullptr, M, 1024, D, D, 2);
    gemm_split<<<gD, blk, 0, stream>>>(ff, W2H, W2L, nullptr, ao, nullptr, nullptr, M, D, 1024, DFF, 1);
    gemm_split<<<gH, blk, 0, stream>>>(h, W1H + 524288, W1L + 524288,
                                       b1 + (size_t)l * DFF + 1024, ff, nullptr, nullptr, M, 1024, D, D, 2);
    gemm_split<<<gD, blk, 0, stream>>>(ff, W2H + 1024, W2L + 1024,
                                       b2 + (size_t)l * D, ao, nullptr, nullptr, M, D, 1024, DFF, 4);

    resid_ln_kernel<<<dim3(4096), blk, 0, stream>>>(h, ao, g2 + (size_t)l * D, be2 + (size_t)l * D);
  }

  head_kernel<<<dim3(4), blk, 0, stream>>>(h, gm, bm, Wm, cm, gs, bs, Ws, cs, (float*)d_out);
}